// Round 12
// baseline (541.288 us; speedup 1.0000x reference)
//
#include <hip/hip_runtime.h>
#include <hip/hip_bf16.h>
#include <math.h>

#define BB    2
#define CC    64
#define VV    180
#define DD    384
#define WOUTN 1024
#define HIDN  256

typedef __attribute__((ext_vector_type(8))) short short8;   // 8 bf16
typedef __attribute__((ext_vector_type(4))) float f32x4;    // MFMA acc

// native RNE conversions (compiler emits v_cvt_pk_bf16_f32 on gfx950)
__device__ __forceinline__ unsigned short f2bf(float f) {
    __hip_bfloat16 h = __float2bfloat16(f);
    return *reinterpret_cast<unsigned short*>(&h);
}
__device__ __forceinline__ float bf2f(unsigned short s) {
    return __uint_as_float(((unsigned int)s) << 16);
}
__device__ __forceinline__ unsigned int pk2bf(float a, float b) {
    __hip_bfloat162 h2 = __float22bfloat162_rn(make_float2(a, b));
    return *reinterpret_cast<unsigned int*>(&h2);
}

// ---------------------------------------------------------------------------
// Kernel 0: weight prep (MLP w0/w1 + combined conv weights -> bf16 fragments)
// ---------------------------------------------------------------------------
__global__ __launch_bounds__(256) void prep_kernel(
    const float* __restrict__ w0, const float* __restrict__ w1,
    const float* __restrict__ wc, const float* __restrict__ wf,
    unsigned short* __restrict__ w0f, unsigned short* __restrict__ w1f,
    unsigned short* __restrict__ wcf)
{
    int idx = blockIdx.x * 256 + threadIdx.x;
    if (idx < 64 * 256) {
        int k = idx >> 8, n = idx & 255;
        int wave = n >> 6, nt = (n >> 4) & 3, lo = n & 15;
        int ks = k >> 5, hi = (k >> 3) & 3, j = k & 7;
        w0f[(size_t)(((wave * 4 + nt) * 2 + ks) * 64 + hi * 16 + lo) * 8 + j] =
            f2bf(w0[k * 256 + n]);
    } else if (idx < 64 * 256 + 256 * 256) {
        int i2 = idx - 64 * 256;
        int k = i2 >> 8, n = i2 & 255;
        int wave = n >> 6, nt = (n >> 4) & 3, lo = n & 15;
        int ks = k >> 5, hi = (k >> 3) & 3, j = k & 7;
        w1f[(size_t)(((wave * 4 + nt) * 8 + ks) * 64 + hi * 16 + lo) * 8 + j] =
            f2bf(w1[k * 256 + n]);
    } else if (idx < 64 * 256 + 256 * 256 + 576 * 128) {
        int i3 = idx - (64 * 256 + 256 * 256);
        int k = i3 >> 7, n = i3 & 127;
        int tap = k >> 6, ic = k & 63;
        int r = tap / 3, t = tap - r * 3;
        int head = n >> 6, oc = n & 63;
        float val = (head ? wf : wc)[((oc * 64 + ic) * 3 + r) * 3 + t];
        int ks = k >> 5, hi = (k >> 3) & 3, j = k & 7;
        int nt = n >> 4, lo = n & 15;
        wcf[(size_t)((ks * 8 + nt) * 64 + hi * 16 + lo) * 8 + j] = f2bf(val);
    }
}

// ---------------------------------------------------------------------------
// Kernel 1: transpose sinogram [b,c,y,x] f32 -> channel-last bf16 [b,y,x,c]
// ---------------------------------------------------------------------------
__global__ __launch_bounds__(256) void transpose_kernel(
    const float* __restrict__ sino, unsigned short* __restrict__ sino_cl)
{
    __shared__ float tile[64][65];
    const int blk = blockIdx.x;
    const int xt = blk % 6;
    const int y  = (blk / 6) % VV;
    const int b  = blk / (6 * VV);
    const int x0 = xt * 64;

    const int x  = threadIdx.x & 63;
    const int cq = threadIdx.x >> 6;
#pragma unroll
    for (int cr = 0; cr < 16; ++cr) {
        const int c = cr * 4 + cq;
        tile[c][x] = sino[((size_t)(b * CC + c) * VV + y) * DD + x0 + x];
    }
    __syncthreads();

    const int xw = threadIdx.x >> 2;
    const int cg = threadIdx.x & 3;
    __align__(16) unsigned short vals[16];
#pragma unroll
    for (int i = 0; i < 16; ++i) vals[i] = f2bf(tile[cg * 16 + i][xw]);
    unsigned short* dst = sino_cl + ((size_t)(b * VV + y) * DD + x0 + xw) * 64 + cg * 16;
    *(short8*)dst       = *(const short8*)&vals[0];
    *((short8*)dst + 1) = *(const short8*)&vals[8];
}

// ---------------------------------------------------------------------------
// Kernel 2: conv as implicit GEMM via MFMA. coef out bf16. (unchanged)
// ---------------------------------------------------------------------------
#define SWZ(x) (((x) & 7) << 4)

__global__ __launch_bounds__(256) void conv_mfma_kernel(
    const unsigned short* __restrict__ sino_cl,
    const unsigned short* __restrict__ wcf,
    const float* __restrict__ bc, const float* __restrict__ bf,
    unsigned short* __restrict__ out_coef, float* __restrict__ out_fsum)
{
    __shared__ __align__(16) unsigned short a_lds[3 * 66 * 64];
    const int blk = blockIdx.x;
    const int xt = blk % 6;
    const int y  = (blk / 6) % VV;
    const int b  = blk / (6 * VV);
    const int x0 = xt * 64;
    const int tid  = threadIdx.x;
    const int wave = tid >> 6;
    const int lane = tid & 63;
    const int lo   = lane & 15;
    const int g    = lane >> 4;

    for (int cc = tid; cc < 1584; cc += 256) {
        const int r   = cc / 528;
        const int rem = cc - r * 528;
        const int x   = rem >> 3;
        const int icg = rem & 7;
        const int gy  = y + r - 1;
        const int gx  = x0 + x - 1;
        short8 v = (short8)0;
        if (gy >= 0 && gy < VV && gx >= 0 && gx < DD)
            v = *(const short8*)(sino_cl + ((size_t)(b * VV + gy) * DD + gx) * 64 + icg * 8);
        const int dst = ((r * 66 + x) * 128 + icg * 16) ^ SWZ(x);
        *(short8*)((char*)a_lds + dst) = v;
    }
    __syncthreads();

    f32x4 acc[4][2];
#pragma unroll
    for (int m = 0; m < 4; ++m) {
        acc[m][0] = (f32x4)0.0f;
        acc[m][1] = (f32x4)0.0f;
    }

#pragma unroll
    for (int ks = 0; ks < 18; ++ks) {
        const int tap = ks >> 1;
        const int r = tap / 3, t = tap - (tap / 3) * 3;
        const short8 wq0 = *(const short8*)(wcf + (size_t)((ks * 8 + wave * 2 + 0) * 64 + lane) * 8);
        const short8 wq1 = *(const short8*)(wcf + (size_t)((ks * 8 + wave * 2 + 1) * 64 + lane) * 8);
        short8 aq[4];
#pragma unroll
        for (int m = 0; m < 4; ++m) {
            const int x = m * 16 + lo + t;
            const int byte = ((r * 66 + x) * 128 + ((ks & 1) * 64 + g * 16)) ^ SWZ(x);
            aq[m] = *(const short8*)((const char*)a_lds + byte);
        }
#pragma unroll
        for (int m = 0; m < 4; ++m) {
            acc[m][0] = __builtin_amdgcn_mfma_f32_16x16x32_bf16(aq[m], wq0, acc[m][0], 0, 0, 0);
            acc[m][1] = __builtin_amdgcn_mfma_f32_16x16x32_bf16(aq[m], wq1, acc[m][1], 0, 0, 0);
        }
    }

    const size_t pixbase = (size_t)(b * VV + y) * DD + x0;
    if (wave < 2) {
#pragma unroll
        for (int nt = 0; nt < 2; ++nt) {
            const int oc = wave * 32 + nt * 16 + lo;
            const float bias = bc[oc];
#pragma unroll
            for (int m = 0; m < 4; ++m)
#pragma unroll
                for (int ri = 0; ri < 4; ++ri) {
                    const int pix = m * 16 + g * 4 + ri;
                    out_coef[(pixbase + pix) * 64 + oc] = f2bf(acc[m][nt][ri] + bias);
                }
        }
    } else {
#pragma unroll
        for (int nt = 0; nt < 2; ++nt) {
            const int ocf = (wave - 2) * 32 + nt * 16 + lo;
            const float bsum = bf[ocf] + bf[ocf ^ 1];
#pragma unroll
            for (int m = 0; m < 4; ++m)
#pragma unroll
                for (int ri = 0; ri < 4; ++ri) {
                    const float v  = acc[m][nt][ri];
                    const float vp = __shfl_xor(v, 1, 64);
                    if ((lo & 1) == 0) {
                        const int pix = m * 16 + g * 4 + ri;
                        out_fsum[(pixbase + pix) * 32 + (ocf >> 1)] = v + vp + bsum;
                    }
                }
        }
    }
}

// ---------------------------------------------------------------------------
// Kernel 3: xbuild — gather + trig, 4 threads per eval. (unchanged)
// ---------------------------------------------------------------------------
__global__ __launch_bounds__(256) void xbuild_kernel(
    const float* __restrict__ grid, const float* __restrict__ fsum,
    const unsigned short* __restrict__ coef_bf,
    const void* __restrict__ scale_p, const float* __restrict__ phase_w,
    unsigned short* __restrict__ X, int vbase)
{
    const int t  = blockIdx.x * 256 + threadIdx.x;
    const int el = t >> 2;
    const int q  = t & 3;

    const int sh = el & 1;
    const int p  = (el >> 1) & 1023;
    const int b  = (el >> 11) & 1;
    const int vl = el >> 12;
    const int v  = vbase + vl;

    int   iv = *(const int*)scale_p;
    float scale = (iv > 0 && iv < 1000000) ? (float)iv : __int_as_float(iv);
    const float cell = 2.0f / scale;
    const float S = (float)(1.0 / 384.0 + 1e-6);
    const float shv = sh ? S : -S;

    const float* gp = &grid[((size_t)(b * VV + v) * WOUTN + p) * 2];
    const float gx = gp[0], gy = gp[1];
    float ix = ((gx + shv + 1.0f) * 384.0f - 1.0f) * 0.5f;
    ix = fminf(fmaxf(ix, 0.0f), 383.0f);
    const int xi = (int)rintf(ix);
    float iy = ((gy + 1.0f) * 180.0f - 1.0f) * 0.5f;
    iy = fminf(fmaxf(iy, 0.0f), 179.0f);
    const int yi = (int)rintf(iy);
    const float det = (2.0f * (float)xi + 1.0f) / 384.0f - 1.0f;
    const float rel = (gx - det) * 384.0f;
    const int base = (b * VV + yi) * DD + xi;

    const int j0 = q * 8;
    const float4 fsa = *(const float4*)(fsum + (size_t)base * 32 + j0);
    const float4 fsb = *(const float4*)(fsum + (size_t)base * 32 + j0 + 4);
    const short8 c0 = *(const short8*)(coef_bf + (size_t)base * 64 + j0);
    const short8 c1 = *(const short8*)(coef_bf + (size_t)base * 64 + 32 + j0);
    const float4 pha = *(const float4*)(phase_w + j0);
    const float4 phb = *(const float4*)(phase_w + j0 + 4);

    float fs[8] = {fsa.x, fsa.y, fsa.z, fsa.w, fsb.x, fsb.y, fsb.z, fsb.w};
    float ph[8] = {pha.x, pha.y, pha.z, pha.w, phb.x, phb.y, phb.z, phb.w};

    __align__(16) unsigned short xc[8], xs[8];
#pragma unroll
    for (int jj = 0; jj < 8; ++jj) {
        const float fr = rel * fs[jj] + cell * ph[jj];
        xc[jj] = f2bf(bf2f((unsigned short)c0[jj]) * cospif(fr));
        xs[jj] = f2bf(bf2f((unsigned short)c1[jj]) * sinpif(fr));
    }
    *(short8*)(X + (size_t)el * 64 + j0)      = *(const short8*)xc;
    *(short8*)(X + (size_t)el * 64 + 32 + j0) = *(const short8*)xs;
}

// ---------------------------------------------------------------------------
// Kernel 4: mlp v8 — R8's proven M=64 structure, LDS trimmed to exactly
// 32 KB by aliasing 'part' onto h_t (R11-validated barrier discipline)
// -> 5 blocks/CU instead of 4.
// ---------------------------------------------------------------------------
__global__ __launch_bounds__(256, 5) void mlp_kernel(
    const unsigned short* __restrict__ X,
    const unsigned short* __restrict__ w0f, const float* __restrict__ b0,
    const unsigned short* __restrict__ w1f, const float* __restrict__ b1,
    const float* __restrict__ w2, const float* __restrict__ b2,
    float* __restrict__ pred)
{
    const int tid  = threadIdx.x;
    const int wave = tid >> 6;
    const int lane = tid & 63;
    const int lo   = lane & 15;
    const int g    = lane >> 4;
    const int m0   = blockIdx.x * 64;

    __shared__ __align__(16) unsigned short h_t[32 * 64 * 8];   // 32 KB exactly
    float (*part)[4] = reinterpret_cast<float (*)[4]>(h_t);     // reused after barrier

    short8 w0q[4][2];
#pragma unroll
    for (int mt = 0; mt < 4; ++mt)
#pragma unroll
        for (int ks = 0; ks < 2; ++ks)
            w0q[mt][ks] = *(const short8*)(w0f + (size_t)(((wave * 4 + mt) * 2 + ks) * 64 + lane) * 8);

    f32x4 acc1[4][4];
#pragma unroll
    for (int mt = 0; mt < 4; ++mt)
#pragma unroll
        for (int nt = 0; nt < 4; ++nt) acc1[mt][nt] = (f32x4)0.0f;

#pragma unroll
    for (int nh = 0; nh < 2; ++nh) {
        short8 bx[2][2];
#pragma unroll
        for (int n2 = 0; n2 < 2; ++n2)
#pragma unroll
            for (int ks = 0; ks < 2; ++ks)
                bx[n2][ks] = *(const short8*)(X + (size_t)(m0 + (nh * 2 + n2) * 16 + lo) * 64 + ks * 32 + g * 8);
#pragma unroll
        for (int mt = 0; mt < 4; ++mt)
#pragma unroll
            for (int n2 = 0; n2 < 2; ++n2) {
                const int nt = nh * 2 + n2;
                acc1[mt][nt] = __builtin_amdgcn_mfma_f32_16x16x32_bf16(w0q[mt][0], bx[n2][0], acc1[mt][nt], 0, 0, 0);
                acc1[mt][nt] = __builtin_amdgcn_mfma_f32_16x16x32_bf16(w0q[mt][1], bx[n2][1], acc1[mt][nt], 0, 0, 0);
            }
    }

#pragma unroll
    for (int mt = 0; mt < 4; ++mt) {
        const int h = wave * 64 + mt * 16 + g * 4;
        const float4 b0h = *(const float4*)(b0 + h);
        const int kb2  = (wave * 16 + mt * 4 + g) >> 1;
        const int half = (g & 1) * 8;
#pragma unroll
        for (int nt = 0; nt < 4; ++nt) {
            const float h0 = fmaxf(acc1[mt][nt][0] + b0h.x, 0.0f);
            const float h1 = fmaxf(acc1[mt][nt][1] + b0h.y, 0.0f);
            const float h2 = fmaxf(acc1[mt][nt][2] + b0h.z, 0.0f);
            const float h3 = fmaxf(acc1[mt][nt][3] + b0h.w, 0.0f);
            uint2 pk;
            pk.x = pk2bf(h0, h1);
            pk.y = pk2bf(h2, h3);
            const int e = (nt * 16 + lo) ^ (kb2 & 7);
            const int byte = kb2 * 1024 + e * 16 + half;
            *(uint2*)((char*)h_t + byte) = pk;
        }
    }
    __syncthreads();

    f32x4 acc2[4][4];
#pragma unroll
    for (int mt = 0; mt < 4; ++mt)
#pragma unroll
        for (int nt = 0; nt < 4; ++nt) acc2[mt][nt] = (f32x4)0.0f;

#pragma unroll
    for (int ks = 0; ks < 8; ++ks) {
        short8 w1k[4];
#pragma unroll
        for (int mt = 0; mt < 4; ++mt)
            w1k[mt] = *(const short8*)(w1f + (size_t)(((wave * 4 + mt) * 8 + ks) * 64 + lane) * 8);
        short8 bh[4];
#pragma unroll
        for (int nt = 0; nt < 4; ++nt) {
            const int kb2 = ks * 4 + g;
            const int e = (nt * 16 + lo) ^ (kb2 & 7);
            bh[nt] = *(const short8*)((const char*)h_t + kb2 * 1024 + e * 16);
        }
#pragma unroll
        for (int mt = 0; mt < 4; ++mt)
#pragma unroll
            for (int nt = 0; nt < 4; ++nt)
                acc2[mt][nt] = __builtin_amdgcn_mfma_f32_16x16x32_bf16(w1k[mt], bh[nt], acc2[mt][nt], 0, 0, 0);
    }

    // all h_t reads complete before 'part' (aliased storage) is written
    __syncthreads();

    float4 b1h[4], w2h[4];
#pragma unroll
    for (int mt = 0; mt < 4; ++mt) {
        const int h = wave * 64 + mt * 16 + g * 4;
        b1h[mt] = *(const float4*)(b1 + h);
        w2h[mt] = *(const float4*)(w2 + h);
    }
    const float b2v = b2[0];

#pragma unroll
    for (int nt = 0; nt < 4; ++nt) {
        float s = 0.0f;
#pragma unroll
        for (int mt = 0; mt < 4; ++mt) {
            s += fmaxf(acc2[mt][nt][0] + b1h[mt].x, 0.0f) * w2h[mt].x;
            s += fmaxf(acc2[mt][nt][1] + b1h[mt].y, 0.0f) * w2h[mt].y;
            s += fmaxf(acc2[mt][nt][2] + b1h[mt].z, 0.0f) * w2h[mt].z;
            s += fmaxf(acc2[mt][nt][3] + b1h[mt].w, 0.0f) * w2h[mt].w;
        }
        s += __shfl_xor(s, 16, 64);
        s += __shfl_xor(s, 32, 64);
        if (g == 0) part[nt * 16 + lo][wave] = s;
    }
    __syncthreads();
    if (tid < 64)
        pred[m0 + tid] = part[tid][0] + part[tid][1] + part[tid][2] + part[tid][3] + b2v;
}

// ---------------------------------------------------------------------------
// Kernel 5: blend — per (b,p): bilinear BP + pred blend, tree-reduce over v.
// ---------------------------------------------------------------------------
__global__ __launch_bounds__(192) void blend_kernel(
    const float* __restrict__ sino, const float* __restrict__ grid,
    const float* __restrict__ sqinv, const float* __restrict__ pred,
    float* __restrict__ out)
{
    __shared__ float red[192];
    const int tid = threadIdx.x;
    const int b   = blockIdx.x >> 10;
    const int p   = blockIdx.x & 1023;
    const int v   = tid;
    const float S = (float)(1.0 / 384.0 + 1e-6);

    float val = 0.0f;
    if (v < VV) {
        const float* gp = &grid[((size_t)(b * VV + v) * WOUTN + p) * 2];
        const float gx = gp[0], gy = gp[1];
        const float sqv = sqinv[(size_t)(b * VV + v) * WOUTN + p];

        float ix = ((gx + 1.0f) * 384.0f - 1.0f) * 0.5f;
        ix = fminf(fmaxf(ix, 0.0f), 383.0f);
        float iy = ((gy + 1.0f) * 180.0f - 1.0f) * 0.5f;
        iy = fminf(fmaxf(iy, 0.0f), 179.0f);
        const float xf = floorf(ix), yf = floorf(iy);
        const float wx = ix - xf, wy = iy - yf;
        const int x0i = (int)xf, y0i = (int)yf;
        const int x1i = min(x0i + 1, 383), y1i = min(y0i + 1, 179);
        const float* im = &sino[(size_t)(b * CC + 32) * VV * DD];
        const float v00 = im[y0i * DD + x0i], v01 = im[y0i * DD + x1i];
        const float v10 = im[y1i * DD + x0i], v11 = im[y1i * DD + x1i];
        const float bp = (v00 * (1.0f - wx) + v01 * wx) * (1.0f - wy)
                       + (v10 * (1.0f - wx) + v11 * wx) * wy;

        float len[2];
#pragma unroll
        for (int sh = 0; sh < 2; ++sh) {
            const float shv = sh ? S : -S;
            float ixs = ((gx + shv + 1.0f) * 384.0f - 1.0f) * 0.5f;
            ixs = fminf(fmaxf(ixs, 0.0f), 383.0f);
            const int xi = (int)rintf(ixs);
            const float det = (2.0f * (float)xi + 1.0f) / 384.0f - 1.0f;
            const float rel = (gx - det) * 384.0f;
            len[sh] = fabsf(rel) + 1e-4f;
        }
        const size_t e0 = ((size_t)(v * BB + b) * WOUTN + p) * 2;
        const float p0 = pred[e0], p1 = pred[e0 + 1];
        const float ret = (p0 * len[1] + p1 * len[0]) / (len[0] + len[1]);
        val = (bp + ret) * sqv * 10000.0f;
    }
    red[tid] = val;
    __syncthreads();
#pragma unroll
    for (int off = 96; off >= 6; off >>= 1) {
        if (tid < off) red[tid] += red[tid + off];
        __syncthreads();
    }
    if (tid == 0) {
        float r = red[0] + red[1] + red[2] + red[3] + red[4] + red[5];
        out[(size_t)b * WOUTN + p] = r;
    }
}

extern "C" void kernel_launch(void* const* d_in, const int* in_sizes, int n_in,
                              void* d_out, int out_size, void* d_ws, size_t ws_size,
                              hipStream_t stream) {
    const float* sino    = (const float*)d_in[0];
    const float* grid    = (const float*)d_in[1];
    const float* sqinv   = (const float*)d_in[2];
    const void*  scale_p = d_in[3];
    const float* coef_w  = (const float*)d_in[4];
    const float* coef_b  = (const float*)d_in[5];
    const float* freq_w  = (const float*)d_in[6];
    const float* freq_b  = (const float*)d_in[7];
    const float* phase_w = (const float*)d_in[8];
    const float* dec_w0  = (const float*)d_in[9];
    const float* dec_b0  = (const float*)d_in[10];
    const float* dec_w1  = (const float*)d_in[11];
    const float* dec_b1  = (const float*)d_in[12];
    const float* dec_w2  = (const float*)d_in[13];
    const float* dec_b2  = (const float*)d_in[14];
    float* out = (float*)d_out;

    const size_t NPIX = (size_t)BB * VV * DD;              // 138240
    float*          ws_fsum = (float*)d_ws;                // NPIX*32 f32
    unsigned short* coef_bf = (unsigned short*)(ws_fsum + NPIX * 32);  // NPIX*64 bf16
    unsigned short* sino_cl = coef_bf + NPIX * 64;         // NPIX*64 bf16
    unsigned short* w0f = sino_cl + NPIX * 64;             // 16384
    unsigned short* w1f = w0f + 64 * 256;                  // 65536
    unsigned short* wcf = w1f + 256 * 256;                 // 73728
    float*          pred = (float*)(wcf + 576 * 128);      // VV*BB*WOUTN*2 f32
    unsigned short* Xs  = (unsigned short*)(pred + (size_t)VV * BB * WOUTN * 2);

    // ws_size-adaptive slicing: fewer, larger slices if workspace allows.
    const size_t fixed_bytes = (size_t)((char*)Xs - (char*)d_ws);
    const size_t x_bytes_per_view = (size_t)BB * WOUTN * 2 * 64 * 2;
    int vsl = 45;
    if (ws_size >= fixed_bytes + 180 * x_bytes_per_view) vsl = 180;
    else if (ws_size >= fixed_bytes + 90 * x_bytes_per_view) vsl = 90;
    const int nsl = VV / vsl;
    const int evsl = vsl * BB * WOUTN * 2;

    prep_kernel<<<(64 * 256 + 256 * 256 + 576 * 128 + 255) / 256, 256, 0, stream>>>(
        dec_w0, dec_w1, coef_w, freq_w, w0f, w1f, wcf);

    transpose_kernel<<<BB * VV * (DD / 64), 256, 0, stream>>>(sino, sino_cl);

    conv_mfma_kernel<<<BB * VV * (DD / 64), 256, 0, stream>>>(
        sino_cl, wcf, coef_b, freq_b, coef_bf, ws_fsum);

    for (int s = 0; s < nsl; ++s) {
        xbuild_kernel<<<evsl / 64, 256, 0, stream>>>(
            grid, ws_fsum, coef_bf, scale_p, phase_w, Xs, s * vsl);
        mlp_kernel<<<evsl / 64, 256, 0, stream>>>(
            Xs, w0f, dec_b0, w1f, dec_b1, dec_w2, dec_b2,
            pred + (size_t)s * evsl);
    }

    blend_kernel<<<BB * WOUTN, 192, 0, stream>>>(sino, grid, sqinv, pred, out);
}

// Round 13
// 246.884 us; speedup vs baseline: 2.1925x; 2.1925x over previous
//
#include <hip/hip_runtime.h>
#include <hip/hip_bf16.h>
#include <math.h>

#define BB    2
#define CC    64
#define VV    180
#define DD    384
#define WOUTN 1024
#define HIDN  256

typedef __attribute__((ext_vector_type(8))) short short8;   // 8 bf16
typedef __attribute__((ext_vector_type(4))) float f32x4;    // MFMA acc

// native RNE conversions (compiler emits v_cvt_pk_bf16_f32 on gfx950)
__device__ __forceinline__ unsigned short f2bf(float f) {
    __hip_bfloat16 h = __float2bfloat16(f);
    return *reinterpret_cast<unsigned short*>(&h);
}
__device__ __forceinline__ float bf2f(unsigned short s) {
    return __uint_as_float(((unsigned int)s) << 16);
}
__device__ __forceinline__ unsigned int pk2bf(float a, float b) {
    __hip_bfloat162 h2 = __float22bfloat162_rn(make_float2(a, b));
    return *reinterpret_cast<unsigned int*>(&h2);
}

// ---------------------------------------------------------------------------
// Kernel 0: weight prep (MLP w0/w1 + combined conv weights -> bf16 fragments)
// ---------------------------------------------------------------------------
__global__ __launch_bounds__(256) void prep_kernel(
    const float* __restrict__ w0, const float* __restrict__ w1,
    const float* __restrict__ wc, const float* __restrict__ wf,
    unsigned short* __restrict__ w0f, unsigned short* __restrict__ w1f,
    unsigned short* __restrict__ wcf)
{
    int idx = blockIdx.x * 256 + threadIdx.x;
    if (idx < 64 * 256) {
        int k = idx >> 8, n = idx & 255;
        int wave = n >> 6, nt = (n >> 4) & 3, lo = n & 15;
        int ks = k >> 5, hi = (k >> 3) & 3, j = k & 7;
        w0f[(size_t)(((wave * 4 + nt) * 2 + ks) * 64 + hi * 16 + lo) * 8 + j] =
            f2bf(w0[k * 256 + n]);
    } else if (idx < 64 * 256 + 256 * 256) {
        int i2 = idx - 64 * 256;
        int k = i2 >> 8, n = i2 & 255;
        int wave = n >> 6, nt = (n >> 4) & 3, lo = n & 15;
        int ks = k >> 5, hi = (k >> 3) & 3, j = k & 7;
        w1f[(size_t)(((wave * 4 + nt) * 8 + ks) * 64 + hi * 16 + lo) * 8 + j] =
            f2bf(w1[k * 256 + n]);
    } else if (idx < 64 * 256 + 256 * 256 + 576 * 128) {
        int i3 = idx - (64 * 256 + 256 * 256);
        int k = i3 >> 7, n = i3 & 127;
        int tap = k >> 6, ic = k & 63;
        int r = tap / 3, t = tap - r * 3;
        int head = n >> 6, oc = n & 63;
        float val = (head ? wf : wc)[((oc * 64 + ic) * 3 + r) * 3 + t];
        int ks = k >> 5, hi = (k >> 3) & 3, j = k & 7;
        int nt = n >> 4, lo = n & 15;
        wcf[(size_t)((ks * 8 + nt) * 64 + hi * 16 + lo) * 8 + j] = f2bf(val);
    }
}

// ---------------------------------------------------------------------------
// Kernel 1: transpose sinogram [b,c,y,x] f32 -> channel-last bf16 [b,y,x,c]
// ---------------------------------------------------------------------------
__global__ __launch_bounds__(256) void transpose_kernel(
    const float* __restrict__ sino, unsigned short* __restrict__ sino_cl)
{
    __shared__ float tile[64][65];
    const int blk = blockIdx.x;
    const int xt = blk % 6;
    const int y  = (blk / 6) % VV;
    const int b  = blk / (6 * VV);
    const int x0 = xt * 64;

    const int x  = threadIdx.x & 63;
    const int cq = threadIdx.x >> 6;
#pragma unroll
    for (int cr = 0; cr < 16; ++cr) {
        const int c = cr * 4 + cq;
        tile[c][x] = sino[((size_t)(b * CC + c) * VV + y) * DD + x0 + x];
    }
    __syncthreads();

    const int xw = threadIdx.x >> 2;
    const int cg = threadIdx.x & 3;
    __align__(16) unsigned short vals[16];
#pragma unroll
    for (int i = 0; i < 16; ++i) vals[i] = f2bf(tile[cg * 16 + i][xw]);
    unsigned short* dst = sino_cl + ((size_t)(b * VV + y) * DD + x0 + xw) * 64 + cg * 16;
    *(short8*)dst       = *(const short8*)&vals[0];
    *((short8*)dst + 1) = *(const short8*)&vals[8];
}

// ---------------------------------------------------------------------------
// Kernel 2: conv as implicit GEMM via MFMA. coef out bf16. (unchanged)
// ---------------------------------------------------------------------------
#define SWZ(x) (((x) & 7) << 4)

__global__ __launch_bounds__(256) void conv_mfma_kernel(
    const unsigned short* __restrict__ sino_cl,
    const unsigned short* __restrict__ wcf,
    const float* __restrict__ bc, const float* __restrict__ bf,
    unsigned short* __restrict__ out_coef, float* __restrict__ out_fsum)
{
    __shared__ __align__(16) unsigned short a_lds[3 * 66 * 64];
    const int blk = blockIdx.x;
    const int xt = blk % 6;
    const int y  = (blk / 6) % VV;
    const int b  = blk / (6 * VV);
    const int x0 = xt * 64;
    const int tid  = threadIdx.x;
    const int wave = tid >> 6;
    const int lane = tid & 63;
    const int lo   = lane & 15;
    const int g    = lane >> 4;

    for (int cc = tid; cc < 1584; cc += 256) {
        const int r   = cc / 528;
        const int rem = cc - r * 528;
        const int x   = rem >> 3;
        const int icg = rem & 7;
        const int gy  = y + r - 1;
        const int gx  = x0 + x - 1;
        short8 v = (short8)0;
        if (gy >= 0 && gy < VV && gx >= 0 && gx < DD)
            v = *(const short8*)(sino_cl + ((size_t)(b * VV + gy) * DD + gx) * 64 + icg * 8);
        const int dst = ((r * 66 + x) * 128 + icg * 16) ^ SWZ(x);
        *(short8*)((char*)a_lds + dst) = v;
    }
    __syncthreads();

    f32x4 acc[4][2];
#pragma unroll
    for (int m = 0; m < 4; ++m) {
        acc[m][0] = (f32x4)0.0f;
        acc[m][1] = (f32x4)0.0f;
    }

#pragma unroll
    for (int ks = 0; ks < 18; ++ks) {
        const int tap = ks >> 1;
        const int r = tap / 3, t = tap - (tap / 3) * 3;
        const short8 wq0 = *(const short8*)(wcf + (size_t)((ks * 8 + wave * 2 + 0) * 64 + lane) * 8);
        const short8 wq1 = *(const short8*)(wcf + (size_t)((ks * 8 + wave * 2 + 1) * 64 + lane) * 8);
        short8 aq[4];
#pragma unroll
        for (int m = 0; m < 4; ++m) {
            const int x = m * 16 + lo + t;
            const int byte = ((r * 66 + x) * 128 + ((ks & 1) * 64 + g * 16)) ^ SWZ(x);
            aq[m] = *(const short8*)((const char*)a_lds + byte);
        }
#pragma unroll
        for (int m = 0; m < 4; ++m) {
            acc[m][0] = __builtin_amdgcn_mfma_f32_16x16x32_bf16(aq[m], wq0, acc[m][0], 0, 0, 0);
            acc[m][1] = __builtin_amdgcn_mfma_f32_16x16x32_bf16(aq[m], wq1, acc[m][1], 0, 0, 0);
        }
    }

    const size_t pixbase = (size_t)(b * VV + y) * DD + x0;
    if (wave < 2) {
#pragma unroll
        for (int nt = 0; nt < 2; ++nt) {
            const int oc = wave * 32 + nt * 16 + lo;
            const float bias = bc[oc];
#pragma unroll
            for (int m = 0; m < 4; ++m)
#pragma unroll
                for (int ri = 0; ri < 4; ++ri) {
                    const int pix = m * 16 + g * 4 + ri;
                    out_coef[(pixbase + pix) * 64 + oc] = f2bf(acc[m][nt][ri] + bias);
                }
        }
    } else {
#pragma unroll
        for (int nt = 0; nt < 2; ++nt) {
            const int ocf = (wave - 2) * 32 + nt * 16 + lo;
            const float bsum = bf[ocf] + bf[ocf ^ 1];
#pragma unroll
            for (int m = 0; m < 4; ++m)
#pragma unroll
                for (int ri = 0; ri < 4; ++ri) {
                    const float v  = acc[m][nt][ri];
                    const float vp = __shfl_xor(v, 1, 64);
                    if ((lo & 1) == 0) {
                        const int pix = m * 16 + g * 4 + ri;
                        out_fsum[(pixbase + pix) * 32 + (ocf >> 1)] = v + vp + bsum;
                    }
                }
        }
    }
}

// ---------------------------------------------------------------------------
// Kernel 3: xbuild — gather + trig, 4 threads per eval. (unchanged)
// ---------------------------------------------------------------------------
__global__ __launch_bounds__(256) void xbuild_kernel(
    const float* __restrict__ grid, const float* __restrict__ fsum,
    const unsigned short* __restrict__ coef_bf,
    const void* __restrict__ scale_p, const float* __restrict__ phase_w,
    unsigned short* __restrict__ X, int vbase)
{
    const int t  = blockIdx.x * 256 + threadIdx.x;
    const int el = t >> 2;
    const int q  = t & 3;

    const int sh = el & 1;
    const int p  = (el >> 1) & 1023;
    const int b  = (el >> 11) & 1;
    const int vl = el >> 12;
    const int v  = vbase + vl;

    int   iv = *(const int*)scale_p;
    float scale = (iv > 0 && iv < 1000000) ? (float)iv : __int_as_float(iv);
    const float cell = 2.0f / scale;
    const float S = (float)(1.0 / 384.0 + 1e-6);
    const float shv = sh ? S : -S;

    const float* gp = &grid[((size_t)(b * VV + v) * WOUTN + p) * 2];
    const float gx = gp[0], gy = gp[1];
    float ix = ((gx + shv + 1.0f) * 384.0f - 1.0f) * 0.5f;
    ix = fminf(fmaxf(ix, 0.0f), 383.0f);
    const int xi = (int)rintf(ix);
    float iy = ((gy + 1.0f) * 180.0f - 1.0f) * 0.5f;
    iy = fminf(fmaxf(iy, 0.0f), 179.0f);
    const int yi = (int)rintf(iy);
    const float det = (2.0f * (float)xi + 1.0f) / 384.0f - 1.0f;
    const float rel = (gx - det) * 384.0f;
    const int base = (b * VV + yi) * DD + xi;

    const int j0 = q * 8;
    const float4 fsa = *(const float4*)(fsum + (size_t)base * 32 + j0);
    const float4 fsb = *(const float4*)(fsum + (size_t)base * 32 + j0 + 4);
    const short8 c0 = *(const short8*)(coef_bf + (size_t)base * 64 + j0);
    const short8 c1 = *(const short8*)(coef_bf + (size_t)base * 64 + 32 + j0);
    const float4 pha = *(const float4*)(phase_w + j0);
    const float4 phb = *(const float4*)(phase_w + j0 + 4);

    float fs[8] = {fsa.x, fsa.y, fsa.z, fsa.w, fsb.x, fsb.y, fsb.z, fsb.w};
    float ph[8] = {pha.x, pha.y, pha.z, pha.w, phb.x, phb.y, phb.z, phb.w};

    __align__(16) unsigned short xc[8], xs[8];
#pragma unroll
    for (int jj = 0; jj < 8; ++jj) {
        const float fr = rel * fs[jj] + cell * ph[jj];
        xc[jj] = f2bf(bf2f((unsigned short)c0[jj]) * cospif(fr));
        xs[jj] = f2bf(bf2f((unsigned short)c1[jj]) * sinpif(fr));
    }
    *(short8*)(X + (size_t)el * 64 + j0)      = *(const short8*)xc;
    *(short8*)(X + (size_t)el * 64 + 32 + j0) = *(const short8*)xs;
}

// ---------------------------------------------------------------------------
// Kernel 4: mlp v9 — R8's proven M=64 structure with 32 KB LDS ('part'
// aliased onto h_t, R11-validated barrier discipline). launch_bounds back
// to (256,4): R12's (256,5) squeezed the register allocator below the
// kernel's ~100 live regs -> spill to scratch (VGPR 48, FETCH x11, 3x slow).
// With natural VGPR=64, LDS=32KB caps residency at 5 blocks/CU anyway.
// ---------------------------------------------------------------------------
__global__ __launch_bounds__(256, 4) void mlp_kernel(
    const unsigned short* __restrict__ X,
    const unsigned short* __restrict__ w0f, const float* __restrict__ b0,
    const unsigned short* __restrict__ w1f, const float* __restrict__ b1,
    const float* __restrict__ w2, const float* __restrict__ b2,
    float* __restrict__ pred)
{
    const int tid  = threadIdx.x;
    const int wave = tid >> 6;
    const int lane = tid & 63;
    const int lo   = lane & 15;
    const int g    = lane >> 4;
    const int m0   = blockIdx.x * 64;

    __shared__ __align__(16) unsigned short h_t[32 * 64 * 8];   // 32 KB exactly
    float (*part)[4] = reinterpret_cast<float (*)[4]>(h_t);     // reused after barrier

    short8 w0q[4][2];
#pragma unroll
    for (int mt = 0; mt < 4; ++mt)
#pragma unroll
        for (int ks = 0; ks < 2; ++ks)
            w0q[mt][ks] = *(const short8*)(w0f + (size_t)(((wave * 4 + mt) * 2 + ks) * 64 + lane) * 8);

    f32x4 acc1[4][4];
#pragma unroll
    for (int mt = 0; mt < 4; ++mt)
#pragma unroll
        for (int nt = 0; nt < 4; ++nt) acc1[mt][nt] = (f32x4)0.0f;

#pragma unroll
    for (int nh = 0; nh < 2; ++nh) {
        short8 bx[2][2];
#pragma unroll
        for (int n2 = 0; n2 < 2; ++n2)
#pragma unroll
            for (int ks = 0; ks < 2; ++ks)
                bx[n2][ks] = *(const short8*)(X + (size_t)(m0 + (nh * 2 + n2) * 16 + lo) * 64 + ks * 32 + g * 8);
#pragma unroll
        for (int mt = 0; mt < 4; ++mt)
#pragma unroll
            for (int n2 = 0; n2 < 2; ++n2) {
                const int nt = nh * 2 + n2;
                acc1[mt][nt] = __builtin_amdgcn_mfma_f32_16x16x32_bf16(w0q[mt][0], bx[n2][0], acc1[mt][nt], 0, 0, 0);
                acc1[mt][nt] = __builtin_amdgcn_mfma_f32_16x16x32_bf16(w0q[mt][1], bx[n2][1], acc1[mt][nt], 0, 0, 0);
            }
    }

#pragma unroll
    for (int mt = 0; mt < 4; ++mt) {
        const int h = wave * 64 + mt * 16 + g * 4;
        const float4 b0h = *(const float4*)(b0 + h);
        const int kb2  = (wave * 16 + mt * 4 + g) >> 1;
        const int half = (g & 1) * 8;
#pragma unroll
        for (int nt = 0; nt < 4; ++nt) {
            const float h0 = fmaxf(acc1[mt][nt][0] + b0h.x, 0.0f);
            const float h1 = fmaxf(acc1[mt][nt][1] + b0h.y, 0.0f);
            const float h2 = fmaxf(acc1[mt][nt][2] + b0h.z, 0.0f);
            const float h3 = fmaxf(acc1[mt][nt][3] + b0h.w, 0.0f);
            uint2 pk;
            pk.x = pk2bf(h0, h1);
            pk.y = pk2bf(h2, h3);
            const int e = (nt * 16 + lo) ^ (kb2 & 7);
            const int byte = kb2 * 1024 + e * 16 + half;
            *(uint2*)((char*)h_t + byte) = pk;
        }
    }
    __syncthreads();

    f32x4 acc2[4][4];
#pragma unroll
    for (int mt = 0; mt < 4; ++mt)
#pragma unroll
        for (int nt = 0; nt < 4; ++nt) acc2[mt][nt] = (f32x4)0.0f;

#pragma unroll
    for (int ks = 0; ks < 8; ++ks) {
        short8 w1k[4];
#pragma unroll
        for (int mt = 0; mt < 4; ++mt)
            w1k[mt] = *(const short8*)(w1f + (size_t)(((wave * 4 + mt) * 8 + ks) * 64 + lane) * 8);
        short8 bh[4];
#pragma unroll
        for (int nt = 0; nt < 4; ++nt) {
            const int kb2 = ks * 4 + g;
            const int e = (nt * 16 + lo) ^ (kb2 & 7);
            bh[nt] = *(const short8*)((const char*)h_t + kb2 * 1024 + e * 16);
        }
#pragma unroll
        for (int mt = 0; mt < 4; ++mt)
#pragma unroll
            for (int nt = 0; nt < 4; ++nt)
                acc2[mt][nt] = __builtin_amdgcn_mfma_f32_16x16x32_bf16(w1k[mt], bh[nt], acc2[mt][nt], 0, 0, 0);
    }

    // all h_t reads complete before 'part' (aliased storage) is written
    __syncthreads();

    float4 b1h[4], w2h[4];
#pragma unroll
    for (int mt = 0; mt < 4; ++mt) {
        const int h = wave * 64 + mt * 16 + g * 4;
        b1h[mt] = *(const float4*)(b1 + h);
        w2h[mt] = *(const float4*)(w2 + h);
    }
    const float b2v = b2[0];

#pragma unroll
    for (int nt = 0; nt < 4; ++nt) {
        float s = 0.0f;
#pragma unroll
        for (int mt = 0; mt < 4; ++mt) {
            s += fmaxf(acc2[mt][nt][0] + b1h[mt].x, 0.0f) * w2h[mt].x;
            s += fmaxf(acc2[mt][nt][1] + b1h[mt].y, 0.0f) * w2h[mt].y;
            s += fmaxf(acc2[mt][nt][2] + b1h[mt].z, 0.0f) * w2h[mt].z;
            s += fmaxf(acc2[mt][nt][3] + b1h[mt].w, 0.0f) * w2h[mt].w;
        }
        s += __shfl_xor(s, 16, 64);
        s += __shfl_xor(s, 32, 64);
        if (g == 0) part[nt * 16 + lo][wave] = s;
    }
    __syncthreads();
    if (tid < 64)
        pred[m0 + tid] = part[tid][0] + part[tid][1] + part[tid][2] + part[tid][3] + b2v;
}

// ---------------------------------------------------------------------------
// Kernel 5: blend — per (b,p): bilinear BP + pred blend, tree-reduce over v.
// ---------------------------------------------------------------------------
__global__ __launch_bounds__(192) void blend_kernel(
    const float* __restrict__ sino, const float* __restrict__ grid,
    const float* __restrict__ sqinv, const float* __restrict__ pred,
    float* __restrict__ out)
{
    __shared__ float red[192];
    const int tid = threadIdx.x;
    const int b   = blockIdx.x >> 10;
    const int p   = blockIdx.x & 1023;
    const int v   = tid;
    const float S = (float)(1.0 / 384.0 + 1e-6);

    float val = 0.0f;
    if (v < VV) {
        const float* gp = &grid[((size_t)(b * VV + v) * WOUTN + p) * 2];
        const float gx = gp[0], gy = gp[1];
        const float sqv = sqinv[(size_t)(b * VV + v) * WOUTN + p];

        float ix = ((gx + 1.0f) * 384.0f - 1.0f) * 0.5f;
        ix = fminf(fmaxf(ix, 0.0f), 383.0f);
        float iy = ((gy + 1.0f) * 180.0f - 1.0f) * 0.5f;
        iy = fminf(fmaxf(iy, 0.0f), 179.0f);
        const float xf = floorf(ix), yf = floorf(iy);
        const float wx = ix - xf, wy = iy - yf;
        const int x0i = (int)xf, y0i = (int)yf;
        const int x1i = min(x0i + 1, 383), y1i = min(y0i + 1, 179);
        const float* im = &sino[(size_t)(b * CC + 32) * VV * DD];
        const float v00 = im[y0i * DD + x0i], v01 = im[y0i * DD + x1i];
        const float v10 = im[y1i * DD + x0i], v11 = im[y1i * DD + x1i];
        const float bp = (v00 * (1.0f - wx) + v01 * wx) * (1.0f - wy)
                       + (v10 * (1.0f - wx) + v11 * wx) * wy;

        float len[2];
#pragma unroll
        for (int sh = 0; sh < 2; ++sh) {
            const float shv = sh ? S : -S;
            float ixs = ((gx + shv + 1.0f) * 384.0f - 1.0f) * 0.5f;
            ixs = fminf(fmaxf(ixs, 0.0f), 383.0f);
            const int xi = (int)rintf(ixs);
            const float det = (2.0f * (float)xi + 1.0f) / 384.0f - 1.0f;
            const float rel = (gx - det) * 384.0f;
            len[sh] = fabsf(rel) + 1e-4f;
        }
        const size_t e0 = ((size_t)(v * BB + b) * WOUTN + p) * 2;
        const float p0 = pred[e0], p1 = pred[e0 + 1];
        const float ret = (p0 * len[1] + p1 * len[0]) / (len[0] + len[1]);
        val = (bp + ret) * sqv * 10000.0f;
    }
    red[tid] = val;
    __syncthreads();
#pragma unroll
    for (int off = 96; off >= 6; off >>= 1) {
        if (tid < off) red[tid] += red[tid + off];
        __syncthreads();
    }
    if (tid == 0) {
        float r = red[0] + red[1] + red[2] + red[3] + red[4] + red[5];
        out[(size_t)b * WOUTN + p] = r;
    }
}

extern "C" void kernel_launch(void* const* d_in, const int* in_sizes, int n_in,
                              void* d_out, int out_size, void* d_ws, size_t ws_size,
                              hipStream_t stream) {
    const float* sino    = (const float*)d_in[0];
    const float* grid    = (const float*)d_in[1];
    const float* sqinv   = (const float*)d_in[2];
    const void*  scale_p = d_in[3];
    const float* coef_w  = (const float*)d_in[4];
    const float* coef_b  = (const float*)d_in[5];
    const float* freq_w  = (const float*)d_in[6];
    const float* freq_b  = (const float*)d_in[7];
    const float* phase_w = (const float*)d_in[8];
    const float* dec_w0  = (const float*)d_in[9];
    const float* dec_b0  = (const float*)d_in[10];
    const float* dec_w1  = (const float*)d_in[11];
    const float* dec_b1  = (const float*)d_in[12];
    const float* dec_w2  = (const float*)d_in[13];
    const float* dec_b2  = (const float*)d_in[14];
    float* out = (float*)d_out;

    const size_t NPIX = (size_t)BB * VV * DD;              // 138240
    float*          ws_fsum = (float*)d_ws;                // NPIX*32 f32
    unsigned short* coef_bf = (unsigned short*)(ws_fsum + NPIX * 32);  // NPIX*64 bf16
    unsigned short* sino_cl = coef_bf + NPIX * 64;         // NPIX*64 bf16
    unsigned short* w0f = sino_cl + NPIX * 64;             // 16384
    unsigned short* w1f = w0f + 64 * 256;                  // 65536
    unsigned short* wcf = w1f + 256 * 256;                 // 73728
    float*          pred = (float*)(wcf + 576 * 128);      // VV*BB*WOUTN*2 f32
    unsigned short* Xs  = (unsigned short*)(pred + (size_t)VV * BB * WOUTN * 2);

    // ws_size-adaptive slicing: fewer, larger slices if workspace allows.
    const size_t fixed_bytes = (size_t)((char*)Xs - (char*)d_ws);
    const size_t x_bytes_per_view = (size_t)BB * WOUTN * 2 * 64 * 2;
    int vsl = 45;
    if (ws_size >= fixed_bytes + 180 * x_bytes_per_view) vsl = 180;
    else if (ws_size >= fixed_bytes + 90 * x_bytes_per_view) vsl = 90;
    const int nsl = VV / vsl;
    const int evsl = vsl * BB * WOUTN * 2;

    prep_kernel<<<(64 * 256 + 256 * 256 + 576 * 128 + 255) / 256, 256, 0, stream>>>(
        dec_w0, dec_w1, coef_w, freq_w, w0f, w1f, wcf);

    transpose_kernel<<<BB * VV * (DD / 64), 256, 0, stream>>>(sino, sino_cl);

    conv_mfma_kernel<<<BB * VV * (DD / 64), 256, 0, stream>>>(
        sino_cl, wcf, coef_b, freq_b, coef_bf, ws_fsum);

    for (int s = 0; s < nsl; ++s) {
        xbuild_kernel<<<evsl / 64, 256, 0, stream>>>(
            grid, ws_fsum, coef_bf, scale_p, phase_w, Xs, s * vsl);
        mlp_kernel<<<evsl / 64, 256, 0, stream>>>(
            Xs, w0f, dec_b0, w1f, dec_b1, dec_w2, dec_b2,
            pred + (size_t)s * evsl);
    }

    blend_kernel<<<BB * WOUTN, 192, 0, stream>>>(sino, grid, sqinv, pred, out);
}

// Round 14
// 199.931 us; speedup vs baseline: 2.7074x; 1.2348x over previous
//
#include <hip/hip_runtime.h>
#include <hip/hip_bf16.h>
#include <math.h>

#define BB    2
#define CC    64
#define VV    180
#define DD    384
#define WOUTN 1024
#define HIDN  256

typedef __attribute__((ext_vector_type(8))) short short8;   // 8 bf16
typedef __attribute__((ext_vector_type(4))) float f32x4;    // MFMA acc

// native RNE conversions (compiler emits v_cvt_pk_bf16_f32 on gfx950)
__device__ __forceinline__ unsigned short f2bf(float f) {
    __hip_bfloat16 h = __float2bfloat16(f);
    return *reinterpret_cast<unsigned short*>(&h);
}
__device__ __forceinline__ float bf2f(unsigned short s) {
    return __uint_as_float(((unsigned int)s) << 16);
}
__device__ __forceinline__ unsigned int pk2bf(float a, float b) {
    __hip_bfloat162 h2 = __float22bfloat162_rn(make_float2(a, b));
    return *reinterpret_cast<unsigned int*>(&h2);
}

// ---------------------------------------------------------------------------
// Kernel 0: weight prep (MLP w0/w1 + combined conv weights -> bf16 fragments)
// ---------------------------------------------------------------------------
__global__ __launch_bounds__(256) void prep_kernel(
    const float* __restrict__ w0, const float* __restrict__ w1,
    const float* __restrict__ wc, const float* __restrict__ wf,
    unsigned short* __restrict__ w0f, unsigned short* __restrict__ w1f,
    unsigned short* __restrict__ wcf)
{
    int idx = blockIdx.x * 256 + threadIdx.x;
    if (idx < 64 * 256) {
        int k = idx >> 8, n = idx & 255;
        int wave = n >> 6, nt = (n >> 4) & 3, lo = n & 15;
        int ks = k >> 5, hi = (k >> 3) & 3, j = k & 7;
        w0f[(size_t)(((wave * 4 + nt) * 2 + ks) * 64 + hi * 16 + lo) * 8 + j] =
            f2bf(w0[k * 256 + n]);
    } else if (idx < 64 * 256 + 256 * 256) {
        int i2 = idx - 64 * 256;
        int k = i2 >> 8, n = i2 & 255;
        int wave = n >> 6, nt = (n >> 4) & 3, lo = n & 15;
        int ks = k >> 5, hi = (k >> 3) & 3, j = k & 7;
        w1f[(size_t)(((wave * 4 + nt) * 8 + ks) * 64 + hi * 16 + lo) * 8 + j] =
            f2bf(w1[k * 256 + n]);
    } else if (idx < 64 * 256 + 256 * 256 + 576 * 128) {
        int i3 = idx - (64 * 256 + 256 * 256);
        int k = i3 >> 7, n = i3 & 127;
        int tap = k >> 6, ic = k & 63;
        int r = tap / 3, t = tap - r * 3;
        int head = n >> 6, oc = n & 63;
        float val = (head ? wf : wc)[((oc * 64 + ic) * 3 + r) * 3 + t];
        int ks = k >> 5, hi = (k >> 3) & 3, j = k & 7;
        int nt = n >> 4, lo = n & 15;
        wcf[(size_t)((ks * 8 + nt) * 64 + hi * 16 + lo) * 8 + j] = f2bf(val);
    }
}

// ---------------------------------------------------------------------------
// Kernel 1: transpose sinogram [b,c,y,x] f32 -> channel-last bf16 [b,y,x,c]
// ---------------------------------------------------------------------------
__global__ __launch_bounds__(256) void transpose_kernel(
    const float* __restrict__ sino, unsigned short* __restrict__ sino_cl)
{
    __shared__ float tile[64][65];
    const int blk = blockIdx.x;
    const int xt = blk % 6;
    const int y  = (blk / 6) % VV;
    const int b  = blk / (6 * VV);
    const int x0 = xt * 64;

    const int x  = threadIdx.x & 63;
    const int cq = threadIdx.x >> 6;
#pragma unroll
    for (int cr = 0; cr < 16; ++cr) {
        const int c = cr * 4 + cq;
        tile[c][x] = sino[((size_t)(b * CC + c) * VV + y) * DD + x0 + x];
    }
    __syncthreads();

    const int xw = threadIdx.x >> 2;
    const int cg = threadIdx.x & 3;
    __align__(16) unsigned short vals[16];
#pragma unroll
    for (int i = 0; i < 16; ++i) vals[i] = f2bf(tile[cg * 16 + i][xw]);
    unsigned short* dst = sino_cl + ((size_t)(b * VV + y) * DD + x0 + xw) * 64 + cg * 16;
    *(short8*)dst       = *(const short8*)&vals[0];
    *((short8*)dst + 1) = *(const short8*)&vals[8];
}

// ---------------------------------------------------------------------------
// Kernel 2: conv as implicit GEMM via MFMA. coef out bf16. (unchanged)
// ---------------------------------------------------------------------------
#define SWZ(x) (((x) & 7) << 4)

__global__ __launch_bounds__(256) void conv_mfma_kernel(
    const unsigned short* __restrict__ sino_cl,
    const unsigned short* __restrict__ wcf,
    const float* __restrict__ bc, const float* __restrict__ bf,
    unsigned short* __restrict__ out_coef, float* __restrict__ out_fsum)
{
    __shared__ __align__(16) unsigned short a_lds[3 * 66 * 64];
    const int blk = blockIdx.x;
    const int xt = blk % 6;
    const int y  = (blk / 6) % VV;
    const int b  = blk / (6 * VV);
    const int x0 = xt * 64;
    const int tid  = threadIdx.x;
    const int wave = tid >> 6;
    const int lane = tid & 63;
    const int lo   = lane & 15;
    const int g    = lane >> 4;

    for (int cc = tid; cc < 1584; cc += 256) {
        const int r   = cc / 528;
        const int rem = cc - r * 528;
        const int x   = rem >> 3;
        const int icg = rem & 7;
        const int gy  = y + r - 1;
        const int gx  = x0 + x - 1;
        short8 v = (short8)0;
        if (gy >= 0 && gy < VV && gx >= 0 && gx < DD)
            v = *(const short8*)(sino_cl + ((size_t)(b * VV + gy) * DD + gx) * 64 + icg * 8);
        const int dst = ((r * 66 + x) * 128 + icg * 16) ^ SWZ(x);
        *(short8*)((char*)a_lds + dst) = v;
    }
    __syncthreads();

    f32x4 acc[4][2];
#pragma unroll
    for (int m = 0; m < 4; ++m) {
        acc[m][0] = (f32x4)0.0f;
        acc[m][1] = (f32x4)0.0f;
    }

#pragma unroll
    for (int ks = 0; ks < 18; ++ks) {
        const int tap = ks >> 1;
        const int r = tap / 3, t = tap - (tap / 3) * 3;
        const short8 wq0 = *(const short8*)(wcf + (size_t)((ks * 8 + wave * 2 + 0) * 64 + lane) * 8);
        const short8 wq1 = *(const short8*)(wcf + (size_t)((ks * 8 + wave * 2 + 1) * 64 + lane) * 8);
        short8 aq[4];
#pragma unroll
        for (int m = 0; m < 4; ++m) {
            const int x = m * 16 + lo + t;
            const int byte = ((r * 66 + x) * 128 + ((ks & 1) * 64 + g * 16)) ^ SWZ(x);
            aq[m] = *(const short8*)((const char*)a_lds + byte);
        }
#pragma unroll
        for (int m = 0; m < 4; ++m) {
            acc[m][0] = __builtin_amdgcn_mfma_f32_16x16x32_bf16(aq[m], wq0, acc[m][0], 0, 0, 0);
            acc[m][1] = __builtin_amdgcn_mfma_f32_16x16x32_bf16(aq[m], wq1, acc[m][1], 0, 0, 0);
        }
    }

    const size_t pixbase = (size_t)(b * VV + y) * DD + x0;
    if (wave < 2) {
#pragma unroll
        for (int nt = 0; nt < 2; ++nt) {
            const int oc = wave * 32 + nt * 16 + lo;
            const float bias = bc[oc];
#pragma unroll
            for (int m = 0; m < 4; ++m)
#pragma unroll
                for (int ri = 0; ri < 4; ++ri) {
                    const int pix = m * 16 + g * 4 + ri;
                    out_coef[(pixbase + pix) * 64 + oc] = f2bf(acc[m][nt][ri] + bias);
                }
        }
    } else {
#pragma unroll
        for (int nt = 0; nt < 2; ++nt) {
            const int ocf = (wave - 2) * 32 + nt * 16 + lo;
            const float bsum = bf[ocf] + bf[ocf ^ 1];
#pragma unroll
            for (int m = 0; m < 4; ++m)
#pragma unroll
                for (int ri = 0; ri < 4; ++ri) {
                    const float v  = acc[m][nt][ri];
                    const float vp = __shfl_xor(v, 1, 64);
                    if ((lo & 1) == 0) {
                        const int pix = m * 16 + g * 4 + ri;
                        out_fsum[(pixbase + pix) * 32 + (ocf >> 1)] = v + vp + bsum;
                    }
                }
        }
    }
}

// ---------------------------------------------------------------------------
// Kernel 3: fused gather+trig+MLP. Block = 64 consecutive evals.
// Phase 0 (from old xbuild): 4 threads/eval gather conv outputs, trig,
// write X into the TOP 8 KB of h_t (swizzled). Then R8's exact M=64 MLP:
// layer1 reads bx frags from that LDS region, barrier, pack h (overwrites
// x region safely), layer2, layer3. LDS = 33,792 B (4 blocks/CU, as R8).
// ---------------------------------------------------------------------------
#define XOFF 24576   // x staged in h_t bytes [24576, 32768)

__global__ __launch_bounds__(256, 4) void mlp_kernel(
    const float* __restrict__ grid, const float* __restrict__ fsum,
    const unsigned short* __restrict__ coef_bf,
    const void* __restrict__ scale_p, const float* __restrict__ phase_w,
    const unsigned short* __restrict__ w0f, const float* __restrict__ b0,
    const unsigned short* __restrict__ w1f, const float* __restrict__ b1,
    const float* __restrict__ w2, const float* __restrict__ b2,
    float* __restrict__ pred)
{
    const int tid  = threadIdx.x;
    const int wave = tid >> 6;
    const int lane = tid & 63;
    const int lo   = lane & 15;
    const int g    = lane >> 4;
    const int m0   = blockIdx.x * 64;

    __shared__ __align__(16) unsigned short h_t[32 * 64 * 8];   // 32 KB
    __shared__ float part[64][4];

    // ---- W0^T A-frags (issue early; overlap with gather) ----
    short8 w0q[4][2];
#pragma unroll
    for (int mt = 0; mt < 4; ++mt)
#pragma unroll
        for (int ks = 0; ks < 2; ++ks)
            w0q[mt][ks] = *(const short8*)(w0f + (size_t)(((wave * 4 + mt) * 2 + ks) * 64 + lane) * 8);

    // ---- Phase 0: gather + trig -> x in h_t[XOFF..] (swizzled rows) ----
    {
        const int r  = tid >> 2;
        const int q  = tid & 3;
        const int el = m0 + r;
        const int sh = el & 1;
        const int p  = (el >> 1) & 1023;
        const int b  = (el >> 11) & 1;
        const int v  = el >> 12;

        int   iv = *(const int*)scale_p;
        float scale = (iv > 0 && iv < 1000000) ? (float)iv : __int_as_float(iv);
        const float cell = 2.0f / scale;
        const float S = (float)(1.0 / 384.0 + 1e-6);
        const float shv = sh ? S : -S;

        const float* gp = &grid[((size_t)(b * VV + v) * WOUTN + p) * 2];
        const float gx = gp[0], gy = gp[1];
        float ix = ((gx + shv + 1.0f) * 384.0f - 1.0f) * 0.5f;
        ix = fminf(fmaxf(ix, 0.0f), 383.0f);
        const int xi = (int)rintf(ix);
        float iy = ((gy + 1.0f) * 180.0f - 1.0f) * 0.5f;
        iy = fminf(fmaxf(iy, 0.0f), 179.0f);
        const int yi = (int)rintf(iy);
        const float det = (2.0f * (float)xi + 1.0f) / 384.0f - 1.0f;
        const float rel = (gx - det) * 384.0f;
        const int base = (b * VV + yi) * DD + xi;

        const int j0 = q * 8;
        const float4 fsa = *(const float4*)(fsum + (size_t)base * 32 + j0);
        const float4 fsb = *(const float4*)(fsum + (size_t)base * 32 + j0 + 4);
        const short8 c0 = *(const short8*)(coef_bf + (size_t)base * 64 + j0);
        const short8 c1 = *(const short8*)(coef_bf + (size_t)base * 64 + 32 + j0);
        const float4 pha = *(const float4*)(phase_w + j0);
        const float4 phb = *(const float4*)(phase_w + j0 + 4);

        float fs[8] = {fsa.x, fsa.y, fsa.z, fsa.w, fsb.x, fsb.y, fsb.z, fsb.w};
        float ph[8] = {pha.x, pha.y, pha.z, pha.w, phb.x, phb.y, phb.z, phb.w};

        __align__(16) unsigned short xc[8], xs[8];
#pragma unroll
        for (int jj = 0; jj < 8; ++jj) {
            const float fr = rel * fs[jj] + cell * ph[jj];
            xc[jj] = f2bf(bf2f((unsigned short)c0[jj]) * cospif(fr));
            xs[jj] = f2bf(bf2f((unsigned short)c1[jj]) * sinpif(fr));
        }
        const int cb = (r * 128 + q * 16) ^ SWZ(r);
        const int sb = (r * 128 + 64 + q * 16) ^ SWZ(r);
        *(short8*)((char*)h_t + XOFF + cb) = *(const short8*)xc;
        *(short8*)((char*)h_t + XOFF + sb) = *(const short8*)xs;
    }
    __syncthreads();

    // ---- layer 1: H^T = W0^T · X^T, bx frags from LDS (2 halves) ----
    f32x4 acc1[4][4];
#pragma unroll
    for (int mt = 0; mt < 4; ++mt)
#pragma unroll
        for (int nt = 0; nt < 4; ++nt) acc1[mt][nt] = (f32x4)0.0f;

#pragma unroll
    for (int nh = 0; nh < 2; ++nh) {
        short8 bx[2][2];
#pragma unroll
        for (int n2 = 0; n2 < 2; ++n2)
#pragma unroll
            for (int ks = 0; ks < 2; ++ks) {
                const int row = (nh * 2 + n2) * 16 + lo;
                const int byte = (row * 128 + ks * 64 + g * 16) ^ SWZ(row);
                bx[n2][ks] = *(const short8*)((const char*)h_t + XOFF + byte);
            }
#pragma unroll
        for (int mt = 0; mt < 4; ++mt)
#pragma unroll
            for (int n2 = 0; n2 < 2; ++n2) {
                const int nt = nh * 2 + n2;
                acc1[mt][nt] = __builtin_amdgcn_mfma_f32_16x16x32_bf16(w0q[mt][0], bx[n2][0], acc1[mt][nt], 0, 0, 0);
                acc1[mt][nt] = __builtin_amdgcn_mfma_f32_16x16x32_bf16(w0q[mt][1], bx[n2][1], acc1[mt][nt], 0, 0, 0);
            }
    }
    // all x reads complete before pack overwrites the x region
    __syncthreads();

    // ---- bias+relu, native cvt_pk, one b64 write per (mt,nt) (swizzled) ----
#pragma unroll
    for (int mt = 0; mt < 4; ++mt) {
        const int h = wave * 64 + mt * 16 + g * 4;
        const float4 b0h = *(const float4*)(b0 + h);
        const int kb2  = (wave * 16 + mt * 4 + g) >> 1;
        const int half = (g & 1) * 8;
#pragma unroll
        for (int nt = 0; nt < 4; ++nt) {
            const float h0 = fmaxf(acc1[mt][nt][0] + b0h.x, 0.0f);
            const float h1 = fmaxf(acc1[mt][nt][1] + b0h.y, 0.0f);
            const float h2 = fmaxf(acc1[mt][nt][2] + b0h.z, 0.0f);
            const float h3 = fmaxf(acc1[mt][nt][3] + b0h.w, 0.0f);
            uint2 pk;
            pk.x = pk2bf(h0, h1);
            pk.y = pk2bf(h2, h3);
            const int e = (nt * 16 + lo) ^ (kb2 & 7);
            const int byte = kb2 * 1024 + e * 16 + half;
            *(uint2*)((char*)h_t + byte) = pk;
        }
    }
    __syncthreads();

    // ---- layer 2: C2^T = W1^T · H^T (w1 streamed; waves hide latency) ----
    f32x4 acc2[4][4];
#pragma unroll
    for (int mt = 0; mt < 4; ++mt)
#pragma unroll
        for (int nt = 0; nt < 4; ++nt) acc2[mt][nt] = (f32x4)0.0f;

#pragma unroll
    for (int ks = 0; ks < 8; ++ks) {
        short8 w1k[4];
#pragma unroll
        for (int mt = 0; mt < 4; ++mt)
            w1k[mt] = *(const short8*)(w1f + (size_t)(((wave * 4 + mt) * 8 + ks) * 64 + lane) * 8);
        short8 bh[4];
#pragma unroll
        for (int nt = 0; nt < 4; ++nt) {
            const int kb2 = ks * 4 + g;
            const int e = (nt * 16 + lo) ^ (kb2 & 7);
            bh[nt] = *(const short8*)((const char*)h_t + kb2 * 1024 + e * 16);
        }
#pragma unroll
        for (int mt = 0; mt < 4; ++mt)
#pragma unroll
            for (int nt = 0; nt < 4; ++nt)
                acc2[mt][nt] = __builtin_amdgcn_mfma_f32_16x16x32_bf16(w1k[mt], bh[nt], acc2[mt][nt], 0, 0, 0);
    }

    // ---- layer 3: load b1/w2 late; in-lane reduce + 2 shfl ----
    float4 b1h[4], w2h[4];
#pragma unroll
    for (int mt = 0; mt < 4; ++mt) {
        const int h = wave * 64 + mt * 16 + g * 4;
        b1h[mt] = *(const float4*)(b1 + h);
        w2h[mt] = *(const float4*)(w2 + h);
    }
    const float b2v = b2[0];

#pragma unroll
    for (int nt = 0; nt < 4; ++nt) {
        float s = 0.0f;
#pragma unroll
        for (int mt = 0; mt < 4; ++mt) {
            s += fmaxf(acc2[mt][nt][0] + b1h[mt].x, 0.0f) * w2h[mt].x;
            s += fmaxf(acc2[mt][nt][1] + b1h[mt].y, 0.0f) * w2h[mt].y;
            s += fmaxf(acc2[mt][nt][2] + b1h[mt].z, 0.0f) * w2h[mt].z;
            s += fmaxf(acc2[mt][nt][3] + b1h[mt].w, 0.0f) * w2h[mt].w;
        }
        s += __shfl_xor(s, 16, 64);
        s += __shfl_xor(s, 32, 64);
        if (g == 0) part[nt * 16 + lo][wave] = s;
    }
    __syncthreads();
    if (tid < 64)
        pred[m0 + tid] = part[tid][0] + part[tid][1] + part[tid][2] + part[tid][3] + b2v;
}

// ---------------------------------------------------------------------------
// Kernel 4: blend — per (b,p): bilinear BP + pred blend, tree-reduce over v.
// ---------------------------------------------------------------------------
__global__ __launch_bounds__(192) void blend_kernel(
    const float* __restrict__ sino, const float* __restrict__ grid,
    const float* __restrict__ sqinv, const float* __restrict__ pred,
    float* __restrict__ out)
{
    __shared__ float red[192];
    const int tid = threadIdx.x;
    const int b   = blockIdx.x >> 10;
    const int p   = blockIdx.x & 1023;
    const int v   = tid;
    const float S = (float)(1.0 / 384.0 + 1e-6);

    float val = 0.0f;
    if (v < VV) {
        const float* gp = &grid[((size_t)(b * VV + v) * WOUTN + p) * 2];
        const float gx = gp[0], gy = gp[1];
        const float sqv = sqinv[(size_t)(b * VV + v) * WOUTN + p];

        float ix = ((gx + 1.0f) * 384.0f - 1.0f) * 0.5f;
        ix = fminf(fmaxf(ix, 0.0f), 383.0f);
        float iy = ((gy + 1.0f) * 180.0f - 1.0f) * 0.5f;
        iy = fminf(fmaxf(iy, 0.0f), 179.0f);
        const float xf = floorf(ix), yf = floorf(iy);
        const float wx = ix - xf, wy = iy - yf;
        const int x0i = (int)xf, y0i = (int)yf;
        const int x1i = min(x0i + 1, 383), y1i = min(y0i + 1, 179);
        const float* im = &sino[(size_t)(b * CC + 32) * VV * DD];
        const float v00 = im[y0i * DD + x0i], v01 = im[y0i * DD + x1i];
        const float v10 = im[y1i * DD + x0i], v11 = im[y1i * DD + x1i];
        const float bp = (v00 * (1.0f - wx) + v01 * wx) * (1.0f - wy)
                       + (v10 * (1.0f - wx) + v11 * wx) * wy;

        float len[2];
#pragma unroll
        for (int sh = 0; sh < 2; ++sh) {
            const float shv = sh ? S : -S;
            float ixs = ((gx + shv + 1.0f) * 384.0f - 1.0f) * 0.5f;
            ixs = fminf(fmaxf(ixs, 0.0f), 383.0f);
            const int xi = (int)rintf(ixs);
            const float det = (2.0f * (float)xi + 1.0f) / 384.0f - 1.0f;
            const float rel = (gx - det) * 384.0f;
            len[sh] = fabsf(rel) + 1e-4f;
        }
        const size_t e0 = ((size_t)(v * BB + b) * WOUTN + p) * 2;
        const float p0 = pred[e0], p1 = pred[e0 + 1];
        const float ret = (p0 * len[1] + p1 * len[0]) / (len[0] + len[1]);
        val = (bp + ret) * sqv * 10000.0f;
    }
    red[tid] = val;
    __syncthreads();
#pragma unroll
    for (int off = 96; off >= 6; off >>= 1) {
        if (tid < off) red[tid] += red[tid + off];
        __syncthreads();
    }
    if (tid == 0) {
        float r = red[0] + red[1] + red[2] + red[3] + red[4] + red[5];
        out[(size_t)b * WOUTN + p] = r;
    }
}

extern "C" void kernel_launch(void* const* d_in, const int* in_sizes, int n_in,
                              void* d_out, int out_size, void* d_ws, size_t ws_size,
                              hipStream_t stream) {
    const float* sino    = (const float*)d_in[0];
    const float* grid    = (const float*)d_in[1];
    const float* sqinv   = (const float*)d_in[2];
    const void*  scale_p = d_in[3];
    const float* coef_w  = (const float*)d_in[4];
    const float* coef_b  = (const float*)d_in[5];
    const float* freq_w  = (const float*)d_in[6];
    const float* freq_b  = (const float*)d_in[7];
    const float* phase_w = (const float*)d_in[8];
    const float* dec_w0  = (const float*)d_in[9];
    const float* dec_b0  = (const float*)d_in[10];
    const float* dec_w1  = (const float*)d_in[11];
    const float* dec_b1  = (const float*)d_in[12];
    const float* dec_w2  = (const float*)d_in[13];
    const float* dec_b2  = (const float*)d_in[14];
    float* out = (float*)d_out;

    const size_t NPIX = (size_t)BB * VV * DD;              // 138240
    float*          ws_fsum = (float*)d_ws;                // NPIX*32 f32
    unsigned short* coef_bf = (unsigned short*)(ws_fsum + NPIX * 32);  // NPIX*64 bf16
    unsigned short* sino_cl = coef_bf + NPIX * 64;         // NPIX*64 bf16
    unsigned short* w0f = sino_cl + NPIX * 64;             // 16384
    unsigned short* w1f = w0f + 64 * 256;                  // 65536
    unsigned short* wcf = w1f + 256 * 256;                 // 73728
    float*          pred = (float*)(wcf + 576 * 128);      // VV*BB*WOUTN*2 f32

    prep_kernel<<<(64 * 256 + 256 * 256 + 576 * 128 + 255) / 256, 256, 0, stream>>>(
        dec_w0, dec_w1, coef_w, freq_w, w0f, w1f, wcf);

    transpose_kernel<<<BB * VV * (DD / 64), 256, 0, stream>>>(sino, sino_cl);

    conv_mfma_kernel<<<BB * VV * (DD / 64), 256, 0, stream>>>(
        sino_cl, wcf, coef_b, freq_b, coef_bf, ws_fsum);

    mlp_kernel<<<VV * BB * WOUTN * 2 / 64, 256, 0, stream>>>(
        grid, ws_fsum, coef_bf, scale_p, phase_w,
        w0f, dec_b0, w1f, dec_b1, dec_w2, dec_b2, pred);

    blend_kernel<<<BB * WOUTN, 192, 0, stream>>>(sino, grid, sqinv, pred, out);
}

// Round 15
// 189.294 us; speedup vs baseline: 2.8595x; 1.0562x over previous
//
#include <hip/hip_runtime.h>
#include <hip/hip_bf16.h>
#include <math.h>

#define BB    2
#define CC    64
#define VV    180
#define DD    384
#define WOUTN 1024
#define HIDN  256

typedef __attribute__((ext_vector_type(8))) short short8;   // 8 bf16
typedef __attribute__((ext_vector_type(4))) float f32x4;    // MFMA acc

// native RNE conversions (compiler emits v_cvt_pk_bf16_f32 on gfx950)
__device__ __forceinline__ unsigned short f2bf(float f) {
    __hip_bfloat16 h = __float2bfloat16(f);
    return *reinterpret_cast<unsigned short*>(&h);
}
__device__ __forceinline__ float bf2f(unsigned short s) {
    return __uint_as_float(((unsigned int)s) << 16);
}
__device__ __forceinline__ unsigned int pk2bf(float a, float b) {
    __hip_bfloat162 h2 = __float22bfloat162_rn(make_float2(a, b));
    return *reinterpret_cast<unsigned int*>(&h2);
}

// hardware trig: v_sin/v_cos take REVOLUTIONS (sin(2*pi*x)); fract-reduce
// first (ISA section 3). sin(pi*f) = v_sin(fract(f/2)) exactly by periodicity.
__device__ __forceinline__ void fast_sincospi(float f, float& s, float& c) {
    const float r = __builtin_amdgcn_fractf(f * 0.5f);
    s = __builtin_amdgcn_sinf(r);
    c = __builtin_amdgcn_cosf(r);
}

// ---------------------------------------------------------------------------
// Kernel 0: weight prep (MLP w0/w1 + combined conv weights -> bf16 fragments)
// ---------------------------------------------------------------------------
__global__ __launch_bounds__(256) void prep_kernel(
    const float* __restrict__ w0, const float* __restrict__ w1,
    const float* __restrict__ wc, const float* __restrict__ wf,
    unsigned short* __restrict__ w0f, unsigned short* __restrict__ w1f,
    unsigned short* __restrict__ wcf)
{
    int idx = blockIdx.x * 256 + threadIdx.x;
    if (idx < 64 * 256) {
        int k = idx >> 8, n = idx & 255;
        int wave = n >> 6, nt = (n >> 4) & 3, lo = n & 15;
        int ks = k >> 5, hi = (k >> 3) & 3, j = k & 7;
        w0f[(size_t)(((wave * 4 + nt) * 2 + ks) * 64 + hi * 16 + lo) * 8 + j] =
            f2bf(w0[k * 256 + n]);
    } else if (idx < 64 * 256 + 256 * 256) {
        int i2 = idx - 64 * 256;
        int k = i2 >> 8, n = i2 & 255;
        int wave = n >> 6, nt = (n >> 4) & 3, lo = n & 15;
        int ks = k >> 5, hi = (k >> 3) & 3, j = k & 7;
        w1f[(size_t)(((wave * 4 + nt) * 8 + ks) * 64 + hi * 16 + lo) * 8 + j] =
            f2bf(w1[k * 256 + n]);
    } else if (idx < 64 * 256 + 256 * 256 + 576 * 128) {
        int i3 = idx - (64 * 256 + 256 * 256);
        int k = i3 >> 7, n = i3 & 127;
        int tap = k >> 6, ic = k & 63;
        int r = tap / 3, t = tap - r * 3;
        int head = n >> 6, oc = n & 63;
        float val = (head ? wf : wc)[((oc * 64 + ic) * 3 + r) * 3 + t];
        int ks = k >> 5, hi = (k >> 3) & 3, j = k & 7;
        int nt = n >> 4, lo = n & 15;
        wcf[(size_t)((ks * 8 + nt) * 64 + hi * 16 + lo) * 8 + j] = f2bf(val);
    }
}

// ---------------------------------------------------------------------------
// Kernel 1: transpose sinogram [b,c,y,x] f32 -> channel-last bf16 [b,y,x,c]
// ---------------------------------------------------------------------------
__global__ __launch_bounds__(256) void transpose_kernel(
    const float* __restrict__ sino, unsigned short* __restrict__ sino_cl)
{
    __shared__ float tile[64][65];
    const int blk = blockIdx.x;
    const int xt = blk % 6;
    const int y  = (blk / 6) % VV;
    const int b  = blk / (6 * VV);
    const int x0 = xt * 64;

    const int x  = threadIdx.x & 63;
    const int cq = threadIdx.x >> 6;
#pragma unroll
    for (int cr = 0; cr < 16; ++cr) {
        const int c = cr * 4 + cq;
        tile[c][x] = sino[((size_t)(b * CC + c) * VV + y) * DD + x0 + x];
    }
    __syncthreads();

    const int xw = threadIdx.x >> 2;
    const int cg = threadIdx.x & 3;
    __align__(16) unsigned short vals[16];
#pragma unroll
    for (int i = 0; i < 16; ++i) vals[i] = f2bf(tile[cg * 16 + i][xw]);
    unsigned short* dst = sino_cl + ((size_t)(b * VV + y) * DD + x0 + xw) * 64 + cg * 16;
    *(short8*)dst       = *(const short8*)&vals[0];
    *((short8*)dst + 1) = *(const short8*)&vals[8];
}

// ---------------------------------------------------------------------------
// Kernel 2: conv as implicit GEMM via MFMA. coef out bf16. (unchanged)
// ---------------------------------------------------------------------------
#define SWZ(x) (((x) & 7) << 4)

__global__ __launch_bounds__(256) void conv_mfma_kernel(
    const unsigned short* __restrict__ sino_cl,
    const unsigned short* __restrict__ wcf,
    const float* __restrict__ bc, const float* __restrict__ bf,
    unsigned short* __restrict__ out_coef, float* __restrict__ out_fsum)
{
    __shared__ __align__(16) unsigned short a_lds[3 * 66 * 64];
    const int blk = blockIdx.x;
    const int xt = blk % 6;
    const int y  = (blk / 6) % VV;
    const int b  = blk / (6 * VV);
    const int x0 = xt * 64;
    const int tid  = threadIdx.x;
    const int wave = tid >> 6;
    const int lane = tid & 63;
    const int lo   = lane & 15;
    const int g    = lane >> 4;

    for (int cc = tid; cc < 1584; cc += 256) {
        const int r   = cc / 528;
        const int rem = cc - r * 528;
        const int x   = rem >> 3;
        const int icg = rem & 7;
        const int gy  = y + r - 1;
        const int gx  = x0 + x - 1;
        short8 v = (short8)0;
        if (gy >= 0 && gy < VV && gx >= 0 && gx < DD)
            v = *(const short8*)(sino_cl + ((size_t)(b * VV + gy) * DD + gx) * 64 + icg * 8);
        const int dst = ((r * 66 + x) * 128 + icg * 16) ^ SWZ(x);
        *(short8*)((char*)a_lds + dst) = v;
    }
    __syncthreads();

    f32x4 acc[4][2];
#pragma unroll
    for (int m = 0; m < 4; ++m) {
        acc[m][0] = (f32x4)0.0f;
        acc[m][1] = (f32x4)0.0f;
    }

#pragma unroll
    for (int ks = 0; ks < 18; ++ks) {
        const int tap = ks >> 1;
        const int r = tap / 3, t = tap - (tap / 3) * 3;
        const short8 wq0 = *(const short8*)(wcf + (size_t)((ks * 8 + wave * 2 + 0) * 64 + lane) * 8);
        const short8 wq1 = *(const short8*)(wcf + (size_t)((ks * 8 + wave * 2 + 1) * 64 + lane) * 8);
        short8 aq[4];
#pragma unroll
        for (int m = 0; m < 4; ++m) {
            const int x = m * 16 + lo + t;
            const int byte = ((r * 66 + x) * 128 + ((ks & 1) * 64 + g * 16)) ^ SWZ(x);
            aq[m] = *(const short8*)((const char*)a_lds + byte);
        }
#pragma unroll
        for (int m = 0; m < 4; ++m) {
            acc[m][0] = __builtin_amdgcn_mfma_f32_16x16x32_bf16(aq[m], wq0, acc[m][0], 0, 0, 0);
            acc[m][1] = __builtin_amdgcn_mfma_f32_16x16x32_bf16(aq[m], wq1, acc[m][1], 0, 0, 0);
        }
    }

    const size_t pixbase = (size_t)(b * VV + y) * DD + x0;
    if (wave < 2) {
#pragma unroll
        for (int nt = 0; nt < 2; ++nt) {
            const int oc = wave * 32 + nt * 16 + lo;
            const float bias = bc[oc];
#pragma unroll
            for (int m = 0; m < 4; ++m)
#pragma unroll
                for (int ri = 0; ri < 4; ++ri) {
                    const int pix = m * 16 + g * 4 + ri;
                    out_coef[(pixbase + pix) * 64 + oc] = f2bf(acc[m][nt][ri] + bias);
                }
        }
    } else {
#pragma unroll
        for (int nt = 0; nt < 2; ++nt) {
            const int ocf = (wave - 2) * 32 + nt * 16 + lo;
            const float bsum = bf[ocf] + bf[ocf ^ 1];
#pragma unroll
            for (int m = 0; m < 4; ++m)
#pragma unroll
                for (int ri = 0; ri < 4; ++ri) {
                    const float v  = acc[m][nt][ri];
                    const float vp = __shfl_xor(v, 1, 64);
                    if ((lo & 1) == 0) {
                        const int pix = m * 16 + g * 4 + ri;
                        out_fsum[(pixbase + pix) * 32 + (ocf >> 1)] = v + vp + bsum;
                    }
                }
        }
    }
}

// ---------------------------------------------------------------------------
// Kernel 3: fused gather+trig+MLP (R14 structure). Phase 0 now uses
// hardware v_sin/v_cos (4 ops/pair vs ~40 for OCML sinpif+cospif).
// ---------------------------------------------------------------------------
#define XOFF 24576   // x staged in h_t bytes [24576, 32768)

__global__ __launch_bounds__(256, 4) void mlp_kernel(
    const float* __restrict__ grid, const float* __restrict__ fsum,
    const unsigned short* __restrict__ coef_bf,
    const void* __restrict__ scale_p, const float* __restrict__ phase_w,
    const unsigned short* __restrict__ w0f, const float* __restrict__ b0,
    const unsigned short* __restrict__ w1f, const float* __restrict__ b1,
    const float* __restrict__ w2, const float* __restrict__ b2,
    float* __restrict__ pred)
{
    const int tid  = threadIdx.x;
    const int wave = tid >> 6;
    const int lane = tid & 63;
    const int lo   = lane & 15;
    const int g    = lane >> 4;
    const int m0   = blockIdx.x * 64;

    __shared__ __align__(16) unsigned short h_t[32 * 64 * 8];   // 32 KB
    __shared__ float part[64][4];

    // ---- W0^T A-frags (issue early; overlap with gather) ----
    short8 w0q[4][2];
#pragma unroll
    for (int mt = 0; mt < 4; ++mt)
#pragma unroll
        for (int ks = 0; ks < 2; ++ks)
            w0q[mt][ks] = *(const short8*)(w0f + (size_t)(((wave * 4 + mt) * 2 + ks) * 64 + lane) * 8);

    // ---- Phase 0: gather + HW trig -> x in h_t[XOFF..] (swizzled rows) ----
    {
        const int r  = tid >> 2;
        const int q  = tid & 3;
        const int el = m0 + r;
        const int sh = el & 1;
        const int p  = (el >> 1) & 1023;
        const int b  = (el >> 11) & 1;
        const int v  = el >> 12;

        int   iv = *(const int*)scale_p;
        float scale = (iv > 0 && iv < 1000000) ? (float)iv : __int_as_float(iv);
        const float cell = 2.0f / scale;
        const float S = (float)(1.0 / 384.0 + 1e-6);
        const float shv = sh ? S : -S;

        const float* gp = &grid[((size_t)(b * VV + v) * WOUTN + p) * 2];
        const float gx = gp[0], gy = gp[1];
        float ix = ((gx + shv + 1.0f) * 384.0f - 1.0f) * 0.5f;
        ix = fminf(fmaxf(ix, 0.0f), 383.0f);
        const int xi = (int)rintf(ix);
        float iy = ((gy + 1.0f) * 180.0f - 1.0f) * 0.5f;
        iy = fminf(fmaxf(iy, 0.0f), 179.0f);
        const int yi = (int)rintf(iy);
        const float det = (2.0f * (float)xi + 1.0f) / 384.0f - 1.0f;
        const float rel = (gx - det) * 384.0f;
        const int base = (b * VV + yi) * DD + xi;

        const int j0 = q * 8;
        const float4 fsa = *(const float4*)(fsum + (size_t)base * 32 + j0);
        const float4 fsb = *(const float4*)(fsum + (size_t)base * 32 + j0 + 4);
        const short8 c0 = *(const short8*)(coef_bf + (size_t)base * 64 + j0);
        const short8 c1 = *(const short8*)(coef_bf + (size_t)base * 64 + 32 + j0);
        const float4 pha = *(const float4*)(phase_w + j0);
        const float4 phb = *(const float4*)(phase_w + j0 + 4);

        float fs[8] = {fsa.x, fsa.y, fsa.z, fsa.w, fsb.x, fsb.y, fsb.z, fsb.w};
        float ph[8] = {pha.x, pha.y, pha.z, pha.w, phb.x, phb.y, phb.z, phb.w};

        __align__(16) unsigned short xc[8], xs[8];
#pragma unroll
        for (int jj = 0; jj < 8; ++jj) {
            const float fr = rel * fs[jj] + cell * ph[jj];
            float sv, cv;
            fast_sincospi(fr, sv, cv);
            xc[jj] = f2bf(bf2f((unsigned short)c0[jj]) * cv);
            xs[jj] = f2bf(bf2f((unsigned short)c1[jj]) * sv);
        }
        const int cb = (r * 128 + q * 16) ^ SWZ(r);
        const int sb = (r * 128 + 64 + q * 16) ^ SWZ(r);
        *(short8*)((char*)h_t + XOFF + cb) = *(const short8*)xc;
        *(short8*)((char*)h_t + XOFF + sb) = *(const short8*)xs;
    }
    __syncthreads();

    // ---- layer 1: H^T = W0^T · X^T, bx frags from LDS (2 halves) ----
    f32x4 acc1[4][4];
#pragma unroll
    for (int mt = 0; mt < 4; ++mt)
#pragma unroll
        for (int nt = 0; nt < 4; ++nt) acc1[mt][nt] = (f32x4)0.0f;

#pragma unroll
    for (int nh = 0; nh < 2; ++nh) {
        short8 bx[2][2];
#pragma unroll
        for (int n2 = 0; n2 < 2; ++n2)
#pragma unroll
            for (int ks = 0; ks < 2; ++ks) {
                const int row = (nh * 2 + n2) * 16 + lo;
                const int byte = (row * 128 + ks * 64 + g * 16) ^ SWZ(row);
                bx[n2][ks] = *(const short8*)((const char*)h_t + XOFF + byte);
            }
#pragma unroll
        for (int mt = 0; mt < 4; ++mt)
#pragma unroll
            for (int n2 = 0; n2 < 2; ++n2) {
                const int nt = nh * 2 + n2;
                acc1[mt][nt] = __builtin_amdgcn_mfma_f32_16x16x32_bf16(w0q[mt][0], bx[n2][0], acc1[mt][nt], 0, 0, 0);
                acc1[mt][nt] = __builtin_amdgcn_mfma_f32_16x16x32_bf16(w0q[mt][1], bx[n2][1], acc1[mt][nt], 0, 0, 0);
            }
    }
    // all x reads complete before pack overwrites the x region
    __syncthreads();

    // ---- bias+relu, native cvt_pk, one b64 write per (mt,nt) (swizzled) ----
#pragma unroll
    for (int mt = 0; mt < 4; ++mt) {
        const int h = wave * 64 + mt * 16 + g * 4;
        const float4 b0h = *(const float4*)(b0 + h);
        const int kb2  = (wave * 16 + mt * 4 + g) >> 1;
        const int half = (g & 1) * 8;
#pragma unroll
        for (int nt = 0; nt < 4; ++nt) {
            const float h0 = fmaxf(acc1[mt][nt][0] + b0h.x, 0.0f);
            const float h1 = fmaxf(acc1[mt][nt][1] + b0h.y, 0.0f);
            const float h2 = fmaxf(acc1[mt][nt][2] + b0h.z, 0.0f);
            const float h3 = fmaxf(acc1[mt][nt][3] + b0h.w, 0.0f);
            uint2 pk;
            pk.x = pk2bf(h0, h1);
            pk.y = pk2bf(h2, h3);
            const int e = (nt * 16 + lo) ^ (kb2 & 7);
            const int byte = kb2 * 1024 + e * 16 + half;
            *(uint2*)((char*)h_t + byte) = pk;
        }
    }
    __syncthreads();

    // ---- layer 2: C2^T = W1^T · H^T (w1 streamed; waves hide latency) ----
    f32x4 acc2[4][4];
#pragma unroll
    for (int mt = 0; mt < 4; ++mt)
#pragma unroll
        for (int nt = 0; nt < 4; ++nt) acc2[mt][nt] = (f32x4)0.0f;

#pragma unroll
    for (int ks = 0; ks < 8; ++ks) {
        short8 w1k[4];
#pragma unroll
        for (int mt = 0; mt < 4; ++mt)
            w1k[mt] = *(const short8*)(w1f + (size_t)(((wave * 4 + mt) * 8 + ks) * 64 + lane) * 8);
        short8 bh[4];
#pragma unroll
        for (int nt = 0; nt < 4; ++nt) {
            const int kb2 = ks * 4 + g;
            const int e = (nt * 16 + lo) ^ (kb2 & 7);
            bh[nt] = *(const short8*)((const char*)h_t + kb2 * 1024 + e * 16);
        }
#pragma unroll
        for (int mt = 0; mt < 4; ++mt)
#pragma unroll
            for (int nt = 0; nt < 4; ++nt)
                acc2[mt][nt] = __builtin_amdgcn_mfma_f32_16x16x32_bf16(w1k[mt], bh[nt], acc2[mt][nt], 0, 0, 0);
    }

    // ---- layer 3: load b1/w2 late; in-lane reduce + 2 shfl ----
    float4 b1h[4], w2h[4];
#pragma unroll
    for (int mt = 0; mt < 4; ++mt) {
        const int h = wave * 64 + mt * 16 + g * 4;
        b1h[mt] = *(const float4*)(b1 + h);
        w2h[mt] = *(const float4*)(w2 + h);
    }
    const float b2v = b2[0];

#pragma unroll
    for (int nt = 0; nt < 4; ++nt) {
        float s = 0.0f;
#pragma unroll
        for (int mt = 0; mt < 4; ++mt) {
            s += fmaxf(acc2[mt][nt][0] + b1h[mt].x, 0.0f) * w2h[mt].x;
            s += fmaxf(acc2[mt][nt][1] + b1h[mt].y, 0.0f) * w2h[mt].y;
            s += fmaxf(acc2[mt][nt][2] + b1h[mt].z, 0.0f) * w2h[mt].z;
            s += fmaxf(acc2[mt][nt][3] + b1h[mt].w, 0.0f) * w2h[mt].w;
        }
        s += __shfl_xor(s, 16, 64);
        s += __shfl_xor(s, 32, 64);
        if (g == 0) part[nt * 16 + lo][wave] = s;
    }
    __syncthreads();
    if (tid < 64)
        pred[m0 + tid] = part[tid][0] + part[tid][1] + part[tid][2] + part[tid][3] + b2v;
}

// ---------------------------------------------------------------------------
// Kernel 4: blend — per (b,p): bilinear BP + pred blend, tree-reduce over v.
// ---------------------------------------------------------------------------
__global__ __launch_bounds__(192) void blend_kernel(
    const float* __restrict__ sino, const float* __restrict__ grid,
    const float* __restrict__ sqinv, const float* __restrict__ pred,
    float* __restrict__ out)
{
    __shared__ float red[192];
    const int tid = threadIdx.x;
    const int b   = blockIdx.x >> 10;
    const int p   = blockIdx.x & 1023;
    const int v   = tid;
    const float S = (float)(1.0 / 384.0 + 1e-6);

    float val = 0.0f;
    if (v < VV) {
        const float* gp = &grid[((size_t)(b * VV + v) * WOUTN + p) * 2];
        const float gx = gp[0], gy = gp[1];
        const float sqv = sqinv[(size_t)(b * VV + v) * WOUTN + p];

        float ix = ((gx + 1.0f) * 384.0f - 1.0f) * 0.5f;
        ix = fminf(fmaxf(ix, 0.0f), 383.0f);
        float iy = ((gy + 1.0f) * 180.0f - 1.0f) * 0.5f;
        iy = fminf(fmaxf(iy, 0.0f), 179.0f);
        const float xf = floorf(ix), yf = floorf(iy);
        const float wx = ix - xf, wy = iy - yf;
        const int x0i = (int)xf, y0i = (int)yf;
        const int x1i = min(x0i + 1, 383), y1i = min(y0i + 1, 179);
        const float* im = &sino[(size_t)(b * CC + 32) * VV * DD];
        const float v00 = im[y0i * DD + x0i], v01 = im[y0i * DD + x1i];
        const float v10 = im[y1i * DD + x0i], v11 = im[y1i * DD + x1i];
        const float bp = (v00 * (1.0f - wx) + v01 * wx) * (1.0f - wy)
                       + (v10 * (1.0f - wx) + v11 * wx) * wy;

        float len[2];
#pragma unroll
        for (int sh = 0; sh < 2; ++sh) {
            const float shv = sh ? S : -S;
            float ixs = ((gx + shv + 1.0f) * 384.0f - 1.0f) * 0.5f;
            ixs = fminf(fmaxf(ixs, 0.0f), 383.0f);
            const int xi = (int)rintf(ixs);
            const float det = (2.0f * (float)xi + 1.0f) / 384.0f - 1.0f;
            const float rel = (gx - det) * 384.0f;
            len[sh] = fabsf(rel) + 1e-4f;
        }
        const size_t e0 = ((size_t)(v * BB + b) * WOUTN + p) * 2;
        const float p0 = pred[e0], p1 = pred[e0 + 1];
        const float ret = (p0 * len[1] + p1 * len[0]) / (len[0] + len[1]);
        val = (bp + ret) * sqv * 10000.0f;
    }
    red[tid] = val;
    __syncthreads();
#pragma unroll
    for (int off = 96; off >= 6; off >>= 1) {
        if (tid < off) red[tid] += red[tid + off];
        __syncthreads();
    }
    if (tid == 0) {
        float r = red[0] + red[1] + red[2] + red[3] + red[4] + red[5];
        out[(size_t)b * WOUTN + p] = r;
    }
}

extern "C" void kernel_launch(void* const* d_in, const int* in_sizes, int n_in,
                              void* d_out, int out_size, void* d_ws, size_t ws_size,
                              hipStream_t stream) {
    const float* sino    = (const float*)d_in[0];
    const float* grid    = (const float*)d_in[1];
    const float* sqinv   = (const float*)d_in[2];
    const void*  scale_p = d_in[3];
    const float* coef_w  = (const float*)d_in[4];
    const float* coef_b  = (const float*)d_in[5];
    const float* freq_w  = (const float*)d_in[6];
    const float* freq_b  = (const float*)d_in[7];
    const float* phase_w = (const float*)d_in[8];
    const float* dec_w0  = (const float*)d_in[9];
    const float* dec_b0  = (const float*)d_in[10];
    const float* dec_w1  = (const float*)d_in[11];
    const float* dec_b1  = (const float*)d_in[12];
    const float* dec_w2  = (const float*)d_in[13];
    const float* dec_b2  = (const float*)d_in[14];
    float* out = (float*)d_out;

    const size_t NPIX = (size_t)BB * VV * DD;              // 138240
    float*          ws_fsum = (float*)d_ws;                // NPIX*32 f32
    unsigned short* coef_bf = (unsigned short*)(ws_fsum + NPIX * 32);  // NPIX*64 bf16
    unsigned short* sino_cl = coef_bf + NPIX * 64;         // NPIX*64 bf16
    unsigned short* w0f = sino_cl + NPIX * 64;             // 16384
    unsigned short* w1f = w0f + 64 * 256;                  // 65536
    unsigned short* wcf = w1f + 256 * 256;                 // 73728
    float*          pred = (float*)(wcf + 576 * 128);      // VV*BB*WOUTN*2 f32

    prep_kernel<<<(64 * 256 + 256 * 256 + 576 * 128 + 255) / 256, 256, 0, stream>>>(
        dec_w0, dec_w1, coef_w, freq_w, w0f, w1f, wcf);

    transpose_kernel<<<BB * VV * (DD / 64), 256, 0, stream>>>(sino, sino_cl);

    conv_mfma_kernel<<<BB * VV * (DD / 64), 256, 0, stream>>>(
        sino_cl, wcf, coef_b, freq_b, coef_bf, ws_fsum);

    mlp_kernel<<<VV * BB * WOUTN * 2 / 64, 256, 0, stream>>>(
        grid, ws_fsum, coef_bf, scale_p, phase_w,
        w0f, dec_b0, w1f, dec_b1, dec_w2, dec_b2, pred);

    blend_kernel<<<BB * WOUTN, 192, 0, stream>>>(sino, grid, sqinv, pred, out);
}

// Round 16
// 186.656 us; speedup vs baseline: 2.8999x; 1.0141x over previous
//
#include <hip/hip_runtime.h>
#include <hip/hip_bf16.h>
#include <math.h>

#define BB    2
#define CC    64
#define VV    180
#define DD    384
#define WOUTN 1024
#define HIDN  256

typedef __attribute__((ext_vector_type(8))) short short8;   // 8 bf16
typedef __attribute__((ext_vector_type(4))) float f32x4;    // MFMA acc

// native RNE conversions (compiler emits v_cvt_pk_bf16_f32 on gfx950)
__device__ __forceinline__ unsigned short f2bf(float f) {
    __hip_bfloat16 h = __float2bfloat16(f);
    return *reinterpret_cast<unsigned short*>(&h);
}
__device__ __forceinline__ float bf2f(unsigned short s) {
    return __uint_as_float(((unsigned int)s) << 16);
}
__device__ __forceinline__ unsigned int pk2bf(float a, float b) {
    __hip_bfloat162 h2 = __float22bfloat162_rn(make_float2(a, b));
    return *reinterpret_cast<unsigned int*>(&h2);
}

// hardware trig: v_sin/v_cos take REVOLUTIONS (sin(2*pi*x)); fract-reduce
// first (ISA section 3). sin(pi*f) = v_sin(fract(f/2)) exactly by periodicity.
__device__ __forceinline__ void fast_sincospi(float f, float& s, float& c) {
    const float r = __builtin_amdgcn_fractf(f * 0.5f);
    s = __builtin_amdgcn_sinf(r);
    c = __builtin_amdgcn_cosf(r);
}

// ---------------------------------------------------------------------------
// Kernel 0: weight prep (MLP w0/w1 + combined conv weights -> bf16 fragments)
// ---------------------------------------------------------------------------
__global__ __launch_bounds__(256) void prep_kernel(
    const float* __restrict__ w0, const float* __restrict__ w1,
    const float* __restrict__ wc, const float* __restrict__ wf,
    unsigned short* __restrict__ w0f, unsigned short* __restrict__ w1f,
    unsigned short* __restrict__ wcf)
{
    int idx = blockIdx.x * 256 + threadIdx.x;
    if (idx < 64 * 256) {
        int k = idx >> 8, n = idx & 255;
        int wave = n >> 6, nt = (n >> 4) & 3, lo = n & 15;
        int ks = k >> 5, hi = (k >> 3) & 3, j = k & 7;
        w0f[(size_t)(((wave * 4 + nt) * 2 + ks) * 64 + hi * 16 + lo) * 8 + j] =
            f2bf(w0[k * 256 + n]);
    } else if (idx < 64 * 256 + 256 * 256) {
        int i2 = idx - 64 * 256;
        int k = i2 >> 8, n = i2 & 255;
        int wave = n >> 6, nt = (n >> 4) & 3, lo = n & 15;
        int ks = k >> 5, hi = (k >> 3) & 3, j = k & 7;
        w1f[(size_t)(((wave * 4 + nt) * 8 + ks) * 64 + hi * 16 + lo) * 8 + j] =
            f2bf(w1[k * 256 + n]);
    } else if (idx < 64 * 256 + 256 * 256 + 576 * 128) {
        int i3 = idx - (64 * 256 + 256 * 256);
        int k = i3 >> 7, n = i3 & 127;
        int tap = k >> 6, ic = k & 63;
        int r = tap / 3, t = tap - r * 3;
        int head = n >> 6, oc = n & 63;
        float val = (head ? wf : wc)[((oc * 64 + ic) * 3 + r) * 3 + t];
        int ks = k >> 5, hi = (k >> 3) & 3, j = k & 7;
        int nt = n >> 4, lo = n & 15;
        wcf[(size_t)((ks * 8 + nt) * 64 + hi * 16 + lo) * 8 + j] = f2bf(val);
    }
}

// ---------------------------------------------------------------------------
// Kernel 1: transpose sinogram [b,c,y,x] f32 -> channel-last bf16 [b,y,x,c]
// ---------------------------------------------------------------------------
__global__ __launch_bounds__(256) void transpose_kernel(
    const float* __restrict__ sino, unsigned short* __restrict__ sino_cl)
{
    __shared__ float tile[64][65];
    const int blk = blockIdx.x;
    const int xt = blk % 6;
    const int y  = (blk / 6) % VV;
    const int b  = blk / (6 * VV);
    const int x0 = xt * 64;

    const int x  = threadIdx.x & 63;
    const int cq = threadIdx.x >> 6;
#pragma unroll
    for (int cr = 0; cr < 16; ++cr) {
        const int c = cr * 4 + cq;
        tile[c][x] = sino[((size_t)(b * CC + c) * VV + y) * DD + x0 + x];
    }
    __syncthreads();

    const int xw = threadIdx.x >> 2;
    const int cg = threadIdx.x & 3;
    __align__(16) unsigned short vals[16];
#pragma unroll
    for (int i = 0; i < 16; ++i) vals[i] = f2bf(tile[cg * 16 + i][xw]);
    unsigned short* dst = sino_cl + ((size_t)(b * VV + y) * DD + x0 + xw) * 64 + cg * 16;
    *(short8*)dst       = *(const short8*)&vals[0];
    *((short8*)dst + 1) = *(const short8*)&vals[8];
}

// ---------------------------------------------------------------------------
// Kernel 2: conv as implicit GEMM via MFMA. coef AND fsum out bf16.
// ---------------------------------------------------------------------------
#define SWZ(x) (((x) & 7) << 4)

__global__ __launch_bounds__(256) void conv_mfma_kernel(
    const unsigned short* __restrict__ sino_cl,
    const unsigned short* __restrict__ wcf,
    const float* __restrict__ bc, const float* __restrict__ bf,
    unsigned short* __restrict__ out_coef, unsigned short* __restrict__ out_fsum)
{
    __shared__ __align__(16) unsigned short a_lds[3 * 66 * 64];
    const int blk = blockIdx.x;
    const int xt = blk % 6;
    const int y  = (blk / 6) % VV;
    const int b  = blk / (6 * VV);
    const int x0 = xt * 64;
    const int tid  = threadIdx.x;
    const int wave = tid >> 6;
    const int lane = tid & 63;
    const int lo   = lane & 15;
    const int g    = lane >> 4;

    for (int cc = tid; cc < 1584; cc += 256) {
        const int r   = cc / 528;
        const int rem = cc - r * 528;
        const int x   = rem >> 3;
        const int icg = rem & 7;
        const int gy  = y + r - 1;
        const int gx  = x0 + x - 1;
        short8 v = (short8)0;
        if (gy >= 0 && gy < VV && gx >= 0 && gx < DD)
            v = *(const short8*)(sino_cl + ((size_t)(b * VV + gy) * DD + gx) * 64 + icg * 8);
        const int dst = ((r * 66 + x) * 128 + icg * 16) ^ SWZ(x);
        *(short8*)((char*)a_lds + dst) = v;
    }
    __syncthreads();

    f32x4 acc[4][2];
#pragma unroll
    for (int m = 0; m < 4; ++m) {
        acc[m][0] = (f32x4)0.0f;
        acc[m][1] = (f32x4)0.0f;
    }

#pragma unroll
    for (int ks = 0; ks < 18; ++ks) {
        const int tap = ks >> 1;
        const int r = tap / 3, t = tap - (tap / 3) * 3;
        const short8 wq0 = *(const short8*)(wcf + (size_t)((ks * 8 + wave * 2 + 0) * 64 + lane) * 8);
        const short8 wq1 = *(const short8*)(wcf + (size_t)((ks * 8 + wave * 2 + 1) * 64 + lane) * 8);
        short8 aq[4];
#pragma unroll
        for (int m = 0; m < 4; ++m) {
            const int x = m * 16 + lo + t;
            const int byte = ((r * 66 + x) * 128 + ((ks & 1) * 64 + g * 16)) ^ SWZ(x);
            aq[m] = *(const short8*)((const char*)a_lds + byte);
        }
#pragma unroll
        for (int m = 0; m < 4; ++m) {
            acc[m][0] = __builtin_amdgcn_mfma_f32_16x16x32_bf16(aq[m], wq0, acc[m][0], 0, 0, 0);
            acc[m][1] = __builtin_amdgcn_mfma_f32_16x16x32_bf16(aq[m], wq1, acc[m][1], 0, 0, 0);
        }
    }

    const size_t pixbase = (size_t)(b * VV + y) * DD + x0;
    if (wave < 2) {
#pragma unroll
        for (int nt = 0; nt < 2; ++nt) {
            const int oc = wave * 32 + nt * 16 + lo;
            const float bias = bc[oc];
#pragma unroll
            for (int m = 0; m < 4; ++m)
#pragma unroll
                for (int ri = 0; ri < 4; ++ri) {
                    const int pix = m * 16 + g * 4 + ri;
                    out_coef[(pixbase + pix) * 64 + oc] = f2bf(acc[m][nt][ri] + bias);
                }
        }
    } else {
#pragma unroll
        for (int nt = 0; nt < 2; ++nt) {
            const int ocf = (wave - 2) * 32 + nt * 16 + lo;
            const float bsum = bf[ocf] + bf[ocf ^ 1];
#pragma unroll
            for (int m = 0; m < 4; ++m)
#pragma unroll
                for (int ri = 0; ri < 4; ++ri) {
                    const float v  = acc[m][nt][ri];
                    const float vp = __shfl_xor(v, 1, 64);
                    if ((lo & 1) == 0) {
                        const int pix = m * 16 + g * 4 + ri;
                        out_fsum[(pixbase + pix) * 32 + (ocf >> 1)] = f2bf(v + vp + bsum);
                    }
                }
        }
    }
}

// ---------------------------------------------------------------------------
// Kernel 3: fused gather+trig+MLP (R15 structure). fsum now bf16: one short8
// gather load instead of two float4 loads.
// ---------------------------------------------------------------------------
#define XOFF 24576   // x staged in h_t bytes [24576, 32768)

__global__ __launch_bounds__(256, 4) void mlp_kernel(
    const float* __restrict__ grid, const unsigned short* __restrict__ fsum,
    const unsigned short* __restrict__ coef_bf,
    const void* __restrict__ scale_p, const float* __restrict__ phase_w,
    const unsigned short* __restrict__ w0f, const float* __restrict__ b0,
    const unsigned short* __restrict__ w1f, const float* __restrict__ b1,
    const float* __restrict__ w2, const float* __restrict__ b2,
    float* __restrict__ pred)
{
    const int tid  = threadIdx.x;
    const int wave = tid >> 6;
    const int lane = tid & 63;
    const int lo   = lane & 15;
    const int g    = lane >> 4;
    const int m0   = blockIdx.x * 64;

    __shared__ __align__(16) unsigned short h_t[32 * 64 * 8];   // 32 KB
    __shared__ float part[64][4];

    // ---- W0^T A-frags (issue early; overlap with gather) ----
    short8 w0q[4][2];
#pragma unroll
    for (int mt = 0; mt < 4; ++mt)
#pragma unroll
        for (int ks = 0; ks < 2; ++ks)
            w0q[mt][ks] = *(const short8*)(w0f + (size_t)(((wave * 4 + mt) * 2 + ks) * 64 + lane) * 8);

    // ---- Phase 0: gather + HW trig -> x in h_t[XOFF..] (swizzled rows) ----
    {
        const int r  = tid >> 2;
        const int q  = tid & 3;
        const int el = m0 + r;
        const int sh = el & 1;
        const int p  = (el >> 1) & 1023;
        const int b  = (el >> 11) & 1;
        const int v  = el >> 12;

        int   iv = *(const int*)scale_p;
        float scale = (iv > 0 && iv < 1000000) ? (float)iv : __int_as_float(iv);
        const float cell = 2.0f / scale;
        const float S = (float)(1.0 / 384.0 + 1e-6);
        const float shv = sh ? S : -S;

        const float* gp = &grid[((size_t)(b * VV + v) * WOUTN + p) * 2];
        const float gx = gp[0], gy = gp[1];
        float ix = ((gx + shv + 1.0f) * 384.0f - 1.0f) * 0.5f;
        ix = fminf(fmaxf(ix, 0.0f), 383.0f);
        const int xi = (int)rintf(ix);
        float iy = ((gy + 1.0f) * 180.0f - 1.0f) * 0.5f;
        iy = fminf(fmaxf(iy, 0.0f), 179.0f);
        const int yi = (int)rintf(iy);
        const float det = (2.0f * (float)xi + 1.0f) / 384.0f - 1.0f;
        const float rel = (gx - det) * 384.0f;
        const int base = (b * VV + yi) * DD + xi;

        const int j0 = q * 8;
        const short8 fsv = *(const short8*)(fsum + (size_t)base * 32 + j0);
        const short8 c0 = *(const short8*)(coef_bf + (size_t)base * 64 + j0);
        const short8 c1 = *(const short8*)(coef_bf + (size_t)base * 64 + 32 + j0);
        const float4 pha = *(const float4*)(phase_w + j0);
        const float4 phb = *(const float4*)(phase_w + j0 + 4);

        float ph[8] = {pha.x, pha.y, pha.z, pha.w, phb.x, phb.y, phb.z, phb.w};

        __align__(16) unsigned short xc[8], xs[8];
#pragma unroll
        for (int jj = 0; jj < 8; ++jj) {
            const float fr = rel * bf2f((unsigned short)fsv[jj]) + cell * ph[jj];
            float sv, cv;
            fast_sincospi(fr, sv, cv);
            xc[jj] = f2bf(bf2f((unsigned short)c0[jj]) * cv);
            xs[jj] = f2bf(bf2f((unsigned short)c1[jj]) * sv);
        }
        const int cb = (r * 128 + q * 16) ^ SWZ(r);
        const int sb = (r * 128 + 64 + q * 16) ^ SWZ(r);
        *(short8*)((char*)h_t + XOFF + cb) = *(const short8*)xc;
        *(short8*)((char*)h_t + XOFF + sb) = *(const short8*)xs;
    }
    __syncthreads();

    // ---- layer 1: H^T = W0^T · X^T, bx frags from LDS (2 halves) ----
    f32x4 acc1[4][4];
#pragma unroll
    for (int mt = 0; mt < 4; ++mt)
#pragma unroll
        for (int nt = 0; nt < 4; ++nt) acc1[mt][nt] = (f32x4)0.0f;

#pragma unroll
    for (int nh = 0; nh < 2; ++nh) {
        short8 bx[2][2];
#pragma unroll
        for (int n2 = 0; n2 < 2; ++n2)
#pragma unroll
            for (int ks = 0; ks < 2; ++ks) {
                const int row = (nh * 2 + n2) * 16 + lo;
                const int byte = (row * 128 + ks * 64 + g * 16) ^ SWZ(row);
                bx[n2][ks] = *(const short8*)((const char*)h_t + XOFF + byte);
            }
#pragma unroll
        for (int mt = 0; mt < 4; ++mt)
#pragma unroll
            for (int n2 = 0; n2 < 2; ++n2) {
                const int nt = nh * 2 + n2;
                acc1[mt][nt] = __builtin_amdgcn_mfma_f32_16x16x32_bf16(w0q[mt][0], bx[n2][0], acc1[mt][nt], 0, 0, 0);
                acc1[mt][nt] = __builtin_amdgcn_mfma_f32_16x16x32_bf16(w0q[mt][1], bx[n2][1], acc1[mt][nt], 0, 0, 0);
            }
    }
    // all x reads complete before pack overwrites the x region
    __syncthreads();

    // ---- bias+relu, native cvt_pk, one b64 write per (mt,nt) (swizzled) ----
#pragma unroll
    for (int mt = 0; mt < 4; ++mt) {
        const int h = wave * 64 + mt * 16 + g * 4;
        const float4 b0h = *(const float4*)(b0 + h);
        const int kb2  = (wave * 16 + mt * 4 + g) >> 1;
        const int half = (g & 1) * 8;
#pragma unroll
        for (int nt = 0; nt < 4; ++nt) {
            const float h0 = fmaxf(acc1[mt][nt][0] + b0h.x, 0.0f);
            const float h1 = fmaxf(acc1[mt][nt][1] + b0h.y, 0.0f);
            const float h2 = fmaxf(acc1[mt][nt][2] + b0h.z, 0.0f);
            const float h3 = fmaxf(acc1[mt][nt][3] + b0h.w, 0.0f);
            uint2 pk;
            pk.x = pk2bf(h0, h1);
            pk.y = pk2bf(h2, h3);
            const int e = (nt * 16 + lo) ^ (kb2 & 7);
            const int byte = kb2 * 1024 + e * 16 + half;
            *(uint2*)((char*)h_t + byte) = pk;
        }
    }
    __syncthreads();

    // ---- layer 2: C2^T = W1^T · H^T (w1 streamed; waves hide latency) ----
    f32x4 acc2[4][4];
#pragma unroll
    for (int mt = 0; mt < 4; ++mt)
#pragma unroll
        for (int nt = 0; nt < 4; ++nt) acc2[mt][nt] = (f32x4)0.0f;

#pragma unroll
    for (int ks = 0; ks < 8; ++ks) {
        short8 w1k[4];
#pragma unroll
        for (int mt = 0; mt < 4; ++mt)
            w1k[mt] = *(const short8*)(w1f + (size_t)(((wave * 4 + mt) * 8 + ks) * 64 + lane) * 8);
        short8 bh[4];
#pragma unroll
        for (int nt = 0; nt < 4; ++nt) {
            const int kb2 = ks * 4 + g;
            const int e = (nt * 16 + lo) ^ (kb2 & 7);
            bh[nt] = *(const short8*)((const char*)h_t + kb2 * 1024 + e * 16);
        }
#pragma unroll
        for (int mt = 0; mt < 4; ++mt)
#pragma unroll
            for (int nt = 0; nt < 4; ++nt)
                acc2[mt][nt] = __builtin_amdgcn_mfma_f32_16x16x32_bf16(w1k[mt], bh[nt], acc2[mt][nt], 0, 0, 0);
    }

    // ---- layer 3: load b1/w2 late; in-lane reduce + 2 shfl ----
    float4 b1h[4], w2h[4];
#pragma unroll
    for (int mt = 0; mt < 4; ++mt) {
        const int h = wave * 64 + mt * 16 + g * 4;
        b1h[mt] = *(const float4*)(b1 + h);
        w2h[mt] = *(const float4*)(w2 + h);
    }
    const float b2v = b2[0];

#pragma unroll
    for (int nt = 0; nt < 4; ++nt) {
        float s = 0.0f;
#pragma unroll
        for (int mt = 0; mt < 4; ++mt) {
            s += fmaxf(acc2[mt][nt][0] + b1h[mt].x, 0.0f) * w2h[mt].x;
            s += fmaxf(acc2[mt][nt][1] + b1h[mt].y, 0.0f) * w2h[mt].y;
            s += fmaxf(acc2[mt][nt][2] + b1h[mt].z, 0.0f) * w2h[mt].z;
            s += fmaxf(acc2[mt][nt][3] + b1h[mt].w, 0.0f) * w2h[mt].w;
        }
        s += __shfl_xor(s, 16, 64);
        s += __shfl_xor(s, 32, 64);
        if (g == 0) part[nt * 16 + lo][wave] = s;
    }
    __syncthreads();
    if (tid < 64)
        pred[m0 + tid] = part[tid][0] + part[tid][1] + part[tid][2] + part[tid][3] + b2v;
}

// ---------------------------------------------------------------------------
// Kernel 4: blend — ONE WAVE per (b,p): lane sums views {v, v+64, v+128},
// then 64-wide butterfly reduce. No LDS, no barriers, deterministic order.
// ---------------------------------------------------------------------------
__global__ __launch_bounds__(64) void blend_kernel(
    const float* __restrict__ sino, const float* __restrict__ grid,
    const float* __restrict__ sqinv, const float* __restrict__ pred,
    float* __restrict__ out)
{
    const int lane = threadIdx.x;
    const int b   = blockIdx.x >> 10;
    const int p   = blockIdx.x & 1023;
    const float S = (float)(1.0 / 384.0 + 1e-6);

    float acc = 0.0f;
#pragma unroll
    for (int vb = 0; vb < 192; vb += 64) {
        const int v = vb + lane;
        if (v < VV) {
            const float* gp = &grid[((size_t)(b * VV + v) * WOUTN + p) * 2];
            const float gx = gp[0], gy = gp[1];
            const float sqv = sqinv[(size_t)(b * VV + v) * WOUTN + p];

            float ix = ((gx + 1.0f) * 384.0f - 1.0f) * 0.5f;
            ix = fminf(fmaxf(ix, 0.0f), 383.0f);
            float iy = ((gy + 1.0f) * 180.0f - 1.0f) * 0.5f;
            iy = fminf(fmaxf(iy, 0.0f), 179.0f);
            const float xf = floorf(ix), yf = floorf(iy);
            const float wx = ix - xf, wy = iy - yf;
            const int x0i = (int)xf, y0i = (int)yf;
            const int x1i = min(x0i + 1, 383), y1i = min(y0i + 1, 179);
            const float* im = &sino[(size_t)(b * CC + 32) * VV * DD];
            const float v00 = im[y0i * DD + x0i], v01 = im[y0i * DD + x1i];
            const float v10 = im[y1i * DD + x0i], v11 = im[y1i * DD + x1i];
            const float bp = (v00 * (1.0f - wx) + v01 * wx) * (1.0f - wy)
                           + (v10 * (1.0f - wx) + v11 * wx) * wy;

            float len[2];
#pragma unroll
            for (int sh = 0; sh < 2; ++sh) {
                const float shv = sh ? S : -S;
                float ixs = ((gx + shv + 1.0f) * 384.0f - 1.0f) * 0.5f;
                ixs = fminf(fmaxf(ixs, 0.0f), 383.0f);
                const int xi = (int)rintf(ixs);
                const float det = (2.0f * (float)xi + 1.0f) / 384.0f - 1.0f;
                const float rel = (gx - det) * 384.0f;
                len[sh] = fabsf(rel) + 1e-4f;
            }
            const size_t e0 = ((size_t)(v * BB + b) * WOUTN + p) * 2;
            const float p0 = pred[e0], p1 = pred[e0 + 1];
            const float ret = (p0 * len[1] + p1 * len[0]) / (len[0] + len[1]);
            acc += (bp + ret) * sqv * 10000.0f;
        }
    }
#pragma unroll
    for (int m = 32; m >= 1; m >>= 1)
        acc += __shfl_xor(acc, m, 64);
    if (lane == 0)
        out[(size_t)b * WOUTN + p] = acc;
}

extern "C" void kernel_launch(void* const* d_in, const int* in_sizes, int n_in,
                              void* d_out, int out_size, void* d_ws, size_t ws_size,
                              hipStream_t stream) {
    const float* sino    = (const float*)d_in[0];
    const float* grid    = (const float*)d_in[1];
    const float* sqinv   = (const float*)d_in[2];
    const void*  scale_p = d_in[3];
    const float* coef_w  = (const float*)d_in[4];
    const float* coef_b  = (const float*)d_in[5];
    const float* freq_w  = (const float*)d_in[6];
    const float* freq_b  = (const float*)d_in[7];
    const float* phase_w = (const float*)d_in[8];
    const float* dec_w0  = (const float*)d_in[9];
    const float* dec_b0  = (const float*)d_in[10];
    const float* dec_w1  = (const float*)d_in[11];
    const float* dec_b1  = (const float*)d_in[12];
    const float* dec_w2  = (const float*)d_in[13];
    const float* dec_b2  = (const float*)d_in[14];
    float* out = (float*)d_out;

    const size_t NPIX = (size_t)BB * VV * DD;                   // 138240
    unsigned short* ws_fsum = (unsigned short*)d_ws;            // NPIX*32 bf16
    unsigned short* coef_bf = ws_fsum + NPIX * 32;              // NPIX*64 bf16
    unsigned short* sino_cl = coef_bf + NPIX * 64;              // NPIX*64 bf16
    unsigned short* w0f = sino_cl + NPIX * 64;                  // 16384
    unsigned short* w1f = w0f + 64 * 256;                       // 65536
    unsigned short* wcf = w1f + 256 * 256;                      // 73728
    float*          pred = (float*)(wcf + 576 * 128);           // VV*BB*WOUTN*2 f32

    prep_kernel<<<(64 * 256 + 256 * 256 + 576 * 128 + 255) / 256, 256, 0, stream>>>(
        dec_w0, dec_w1, coef_w, freq_w, w0f, w1f, wcf);

    transpose_kernel<<<BB * VV * (DD / 64), 256, 0, stream>>>(sino, sino_cl);

    conv_mfma_kernel<<<BB * VV * (DD / 64), 256, 0, stream>>>(
        sino_cl, wcf, coef_b, freq_b, coef_bf, ws_fsum);

    mlp_kernel<<<VV * BB * WOUTN * 2 / 64, 256, 0, stream>>>(
        grid, ws_fsum, coef_bf, scale_p, phase_w,
        w0f, dec_b0, w1f, dec_b1, dec_w2, dec_b2, pred);

    blend_kernel<<<BB * WOUTN, 64, 0, stream>>>(sino, grid, sqinv, pred, out);
}